// Round 15
// baseline (219.366 us; speedup 1.0000x reference)
//
#include <hip/hip_runtime.h>
#include <hip/hip_bf16.h>
#include <math.h>

// ---------------------------------------------------------------------------
// GAT 2-layer forward, MI355X.
// R14->R15: l2fused de-LDS'd. R14: 67KB LDS -> 2 blocks/CU (16% occupancy),
// 9 barriers serialized -> 55us at 4% MfmaUtil. Now only the P-tile
// (C->A layout transpose) lives in LDS (one 64x136 buffer, stride-72 view
// for P, stride-136 view for epilogue h2 staging; 17.4KB). A1 / W1th / W2t /
// Qt2 operands are read as MFMA fragments directly from global (each frag =
// contiguous 16B load; weights are L2-resident). 2 barriers/head.
// Everything else unchanged from R14.
// ---------------------------------------------------------------------------

#define NEG_SLOPE 0.2f
#define NB 256        // coarse buckets
#define CH 8192       // edges per binning block

typedef short short8 __attribute__((ext_vector_type(8)));
typedef float float4v __attribute__((ext_vector_type(4)));
typedef float float2v __attribute__((ext_vector_type(2)));

static __device__ __forceinline__ float lrelu(float v) {
    return v > 0.f ? v : NEG_SLOPE * v;
}

static __device__ __forceinline__ unsigned short f2bf(float f) {
    unsigned int u = __float_as_uint(f);
    u = (u + 0x7fffu + ((u >> 16) & 1u)) >> 16;
    return (unsigned short)u;
}
static __device__ __forceinline__ float bf2f(unsigned int lo16) {
    return __uint_as_float(lo16 << 16);
}

static __device__ __forceinline__ int bucket_of(int d, unsigned int M) {
    return (int)(((unsigned long long)(unsigned int)d * M) >> 32);
}

// packed step for agg1x
static __device__ __forceinline__ void pk_step(float2v& a00, float2v& a01,
                                               float2v& a10, float2v& a11,
                                               float2v& d0, float2v& d1,
                                               float4 w, unsigned int v) {
    float2v w01; w01[0] = w.x; w01[1] = w.y;
    float2v w23; w23[0] = w.z; w23[1] = w.w;
    float x0 = __uint_as_float(v << 16);
    float x1 = __uint_as_float(v & 0xffff0000u);
    float2v xx0 = {x0, x0};
    float2v xx1 = {x1, x1};
    asm("v_pk_fma_f32 %0, %1, %2, %0" : "+v"(a00) : "v"(w01), "v"(xx0));
    asm("v_pk_fma_f32 %0, %1, %2, %0" : "+v"(a01) : "v"(w23), "v"(xx0));
    asm("v_pk_fma_f32 %0, %1, %2, %0" : "+v"(a10) : "v"(w01), "v"(xx1));
    asm("v_pk_fma_f32 %0, %1, %2, %0" : "+v"(a11) : "v"(w23), "v"(xx1));
    asm("v_pk_add_f32 %0, %1, %0" : "+v"(d0) : "v"(w01));
    asm("v_pk_add_f32 %0, %1, %0" : "+v"(d1) : "v"(w23));
}

// ---------------------------- P1: bucket histogram + wprep -----------------

__global__ __launch_bounds__(256) void histbin_kernel(
        const int* __restrict__ dst, int* __restrict__ bcnt,
        int E, unsigned int M, int nblk,
        const float* __restrict__ W1, const float* __restrict__ al1,
        const float* __restrict__ ar1, const float* __restrict__ W2,
        const float* __restrict__ al2, const float* __restrict__ ar2,
        unsigned short* __restrict__ W1th, unsigned short* __restrict__ Qt1,
        unsigned short* __restrict__ Qt2, unsigned short* __restrict__ W2t) {
    int b = blockIdx.x;
    int tid = threadIdx.x;
    if (b < nblk) {
        __shared__ int lcnt[NB];
        lcnt[tid] = 0;
        __syncthreads();
        int e0 = b * CH;
        for (int i = tid; i < CH; i += 256) {
            int e = e0 + i;
            if (e < E) atomicAdd(&lcnt[bucket_of(dst[e], M)], 1);
        }
        __syncthreads();
        bcnt[b * NB + tid] = lcnt[tid];
        return;
    }
    int idx = (b - nblk) * 256 + tid;
    if (idx < 32768) {                       // W1th [4][64][128]
        int h = idx >> 13;
        int r = idx & 8191;
        int d = r >> 7, k = r & 127;
        W1th[idx] = f2bf(W1[k * 256 + h * 64 + d]);
    } else if (idx < 34816) {                // Qt1 [16][128]
        int j = idx - 32768;
        int c = j >> 7, k = j & 127;
        float s = 0.f;
        if (c < 8) {
            int h = c & 3;
            const float* av = ((c < 4) ? al1 : ar1) + h * 64;
            const float* wrow = W1 + k * 256 + h * 64;
            #pragma unroll 8
            for (int d = 0; d < 64; ++d) s += wrow[d] * av[d];
        }
        Qt1[j] = f2bf(s);
    } else if (idx < 36864) {                // Qt2 [16][128]
        int j = idx - 34816;
        int c = j >> 7, k = j & 127;
        float s = (c == 0) ? al2[k] : (c == 1) ? ar2[k] : 0.f;
        Qt2[j] = f2bf(s);
    } else if (idx < 69632) {                // W2t [128][256]
        int j = idx - 36864;
        int m = j >> 8, k = j & 255;
        W2t[(size_t)m * 256 + k] = f2bf(W2[(size_t)k * 128 + m]);
    }
}

// ---------------------------- P2: bin scan (1 block) -----------------------

__global__ __launch_bounds__(256) void binscan_kernel(
        const int* __restrict__ bcnt, int* __restrict__ cur0,
        int* __restrict__ bucketStart, int nblk, int E) {
    __shared__ int s[NB];
    int t = threadIdx.x;
    int tot = 0;
    for (int blk = 0; blk < nblk; ++blk) tot += bcnt[blk * NB + t];
    s[t] = tot;
    __syncthreads();
    for (int off = 1; off < NB; off <<= 1) {
        int add = (t >= off) ? s[t - off] : 0;
        __syncthreads();
        s[t] += add;
        __syncthreads();
    }
    const int bs = s[t] - tot;  // exclusive
    bucketStart[t] = bs;
    if (t == NB - 1) bucketStart[NB] = E;
    int run = bs;
    for (int blk = 0; blk < nblk; ++blk) {
        int c = bcnt[blk * NB + t];
        cur0[blk * NB + t] = run;
        run += c;
    }
}

// ------------- P3: fused {binscatter (abs cursors)} | xdots ----------------

__global__ __launch_bounds__(256) void scatxdots_kernel(
        const int* __restrict__ src, const int* __restrict__ dst,
        const int* __restrict__ cur0,
        uint2* __restrict__ pairs, int E, unsigned int M, int nblk,
        const float* __restrict__ x, const unsigned short* __restrict__ Qt,
        unsigned short* __restrict__ xb,
        float* __restrict__ el, float* __restrict__ er, int N) {
    constexpr int KP = 136;
    __shared__ alignas(16) unsigned char smem[(64 + 16) * KP * 2];
    const int tid = threadIdx.x;
    if (blockIdx.x < (unsigned)nblk) {
        int* cur = (int*)smem;           // [NB]
        const int b = blockIdx.x;
        cur[tid] = cur0[b * NB + tid];
        __syncthreads();
        int e0 = b * CH;
        for (int i = tid; i < CH; i += 256) {
            int e = e0 + i;
            if (e < E) {
                int d = dst[e];
                int bk = bucket_of(d, M);
                int pos = atomicAdd(&cur[bk], 1);
                pairs[pos] = make_uint2((unsigned int)src[e], (unsigned int)d);
            }
        }
        return;
    }
    // ---- xdots role ----
    unsigned short* As = (unsigned short*)smem;        // [64*KP]
    unsigned short* Bs = As + 64 * KP;                 // [16*KP]
    const int wid = tid >> 6, lane = tid & 63;
    const int r0 = (blockIdx.x - nblk) * 64;
    for (int ch = tid; ch < 64 * 16; ch += 256) {
        int row = ch >> 4, kc = ch & 15;
        int gr = r0 + row;
        short8 v = {};
        if (gr < N) {
            float4 a = *(const float4*)(x + (size_t)gr * 128 + kc * 8);
            float4 b = *(const float4*)(x + (size_t)gr * 128 + kc * 8 + 4);
            v[0] = (short)f2bf(a.x); v[1] = (short)f2bf(a.y);
            v[2] = (short)f2bf(a.z); v[3] = (short)f2bf(a.w);
            v[4] = (short)f2bf(b.x); v[5] = (short)f2bf(b.y);
            v[6] = (short)f2bf(b.z); v[7] = (short)f2bf(b.w);
            *(short8*)(xb + (size_t)gr * 128 + kc * 8) = v;
        }
        *(short8*)(As + row * KP + kc * 8) = v;
    }
    {
        int row = tid >> 4, kc = tid & 15;
        *(short8*)(Bs + row * KP + kc * 8) = *(const short8*)(Qt + row * 128 + kc * 8);
    }
    __syncthreads();
    float4v acc = (float4v){0.f, 0.f, 0.f, 0.f};
    const int lr = lane & 15, lk = (lane >> 4) * 8;
    #pragma unroll
    for (int ks = 0; ks < 128; ks += 32) {
        short8 af = *(const short8*)(As + (wid * 16 + lr) * KP + ks + lk);
        short8 bf_ = *(const short8*)(Bs + lr * KP + ks + lk);
        acc = __builtin_amdgcn_mfma_f32_16x16x32_bf16(af, bf_, acc, 0, 0, 0);
    }
    const int rbase = r0 + wid * 16 + (lane >> 4) * 4;
    #pragma unroll
    for (int j = 0; j < 4; ++j) {
        int row = rbase + j;
        if (row < N) {
            if (lr < 4) el[(size_t)row * 4 + lr] = acc[j];
            else if (lr < 8) er[(size_t)row * 4 + (lr - 4)] = acc[j];
        }
    }
}

// ---------------------------- P4: per-bucket CSR ---------------------------

__global__ __launch_bounds__(256) void bucketcsr_kernel(
        const uint2* __restrict__ pairs, const int* __restrict__ bucketStart,
        int* __restrict__ row_start, int* __restrict__ srcs,
        int N, int npb, int E) {
    __shared__ int cnt[NB];
    __shared__ int sc[NB];
    int b = blockIdx.x;
    int tid = threadIdx.x;
    int nb0 = b * npb;
    int es = bucketStart[b], ee = bucketStart[b + 1];
    cnt[tid] = 0;
    __syncthreads();
    for (int i = es + tid; i < ee; i += 256) {
        uint2 p = pairs[i];
        atomicAdd(&cnt[(int)p.y - nb0], 1);
    }
    __syncthreads();
    int myc = cnt[tid];
    sc[tid] = myc;
    __syncthreads();
    for (int off = 1; off < NB; off <<= 1) {
        int add = (tid >= off) ? sc[tid - off] : 0;
        __syncthreads();
        sc[tid] += add;
        __syncthreads();
    }
    int excl = sc[tid] - myc;
    int n = nb0 + tid;
    if (n < N && tid < npb) row_start[n] = es + excl;
    if (b == gridDim.x - 1 && tid == 0) row_start[N] = E;
    cnt[tid] = es + excl;   // reuse as cursor
    __syncthreads();
    for (int i = es + tid; i < ee; i += 256) {
        uint2 p = pairs[i];
        int pos = atomicAdd(&cnt[(int)p.y - nb0], 1);
        srcs[pos] = (int)p.x;
    }
}

// ---------------------------- agg1 in x-space (LDS-table + pk math) --------

__global__ __launch_bounds__(256) void agg1x_kernel(const unsigned short* __restrict__ xb,
                            const float* __restrict__ el, const float* __restrict__ er,
                            const int* __restrict__ srcs, const int* __restrict__ row_start,
                            unsigned short* __restrict__ A1, int N) {
    __shared__ int   s_tbl[4][64];
    __shared__ float a_tbl[4][64][4];
    const int wslot = threadIdx.x >> 6;
    const int lane = threadIdx.x & 63;
    const int n = (blockIdx.x * 256 + threadIdx.x) >> 6;
    if (n >= N) return;
    const int rs = row_start[n];
    const int re = row_start[n + 1];

    float2v accP[2][2];
    accP[0][0] = (float2v){0.f, 0.f}; accP[0][1] = (float2v){0.f, 0.f};
    accP[1][0] = (float2v){0.f, 0.f}; accP[1][1] = (float2v){0.f, 0.f};
    float2v dP[2];
    dP[0] = (float2v){0.f, 0.f}; dP[1] = (float2v){0.f, 0.f};

    if (re > rs) {
        const float4 ern = *(const float4*)(er + (size_t)n * 4);
        for (int base = rs; base < re; base += 64) {
            const int cnt = (re - base) < 64 ? (re - base) : 64;
            asm volatile("s_waitcnt lgkmcnt(0)" ::: "memory");
            if (lane < cnt) {
                int sv = srcs[base + lane];
                float4 ev = *(const float4*)(el + (size_t)sv * 4);
                float4 av;
                av.x = __expf(lrelu(ev.x + ern.x));
                av.y = __expf(lrelu(ev.y + ern.y));
                av.z = __expf(lrelu(ev.z + ern.z));
                av.w = __expf(lrelu(ev.w + ern.w));
                s_tbl[wslot][lane] = sv;
                *(float4*)&a_tbl[wslot][lane][0] = av;
            }
            asm volatile("s_waitcnt lgkmcnt(0)" ::: "memory");
            int i = 0;
            for (; i + 4 <= cnt; i += 4) {
                int s0 = s_tbl[wslot][i],     s1 = s_tbl[wslot][i + 1];
                int s2 = s_tbl[wslot][i + 2], s3 = s_tbl[wslot][i + 3];
                float4 w0 = *(const float4*)&a_tbl[wslot][i][0];
                float4 w1 = *(const float4*)&a_tbl[wslot][i + 1][0];
                float4 w2 = *(const float4*)&a_tbl[wslot][i + 2][0];
                float4 w3 = *(const float4*)&a_tbl[wslot][i + 3][0];
                unsigned int v0 = *(const unsigned int*)(xb + (size_t)s0 * 128 + lane * 2);
                unsigned int v1 = *(const unsigned int*)(xb + (size_t)s1 * 128 + lane * 2);
                unsigned int v2 = *(const unsigned int*)(xb + (size_t)s2 * 128 + lane * 2);
                unsigned int v3 = *(const unsigned int*)(xb + (size_t)s3 * 128 + lane * 2);
                pk_step(accP[0][0], accP[0][1], accP[1][0], accP[1][1], dP[0], dP[1], w0, v0);
                pk_step(accP[0][0], accP[0][1], accP[1][0], accP[1][1], dP[0], dP[1], w1, v1);
                pk_step(accP[0][0], accP[0][1], accP[1][0], accP[1][1], dP[0], dP[1], w2, v2);
                pk_step(accP[0][0], accP[0][1], accP[1][0], accP[1][1], dP[0], dP[1], w3, v3);
            }
            for (; i < cnt; ++i) {
                int s0 = s_tbl[wslot][i];
                float4 w = *(const float4*)&a_tbl[wslot][i][0];
                unsigned int v = *(const unsigned int*)(xb + (size_t)s0 * 128 + lane * 2);
                pk_step(accP[0][0], accP[0][1], accP[1][0], accP[1][1], dP[0], dP[1], w, v);
            }
        }
        float i0 = 1.f / dP[0][0], i1 = 1.f / dP[0][1];
        float i2 = 1.f / dP[1][0], i3 = 1.f / dP[1][1];
        accP[0][0][0] *= i0; accP[1][0][0] *= i0;
        accP[0][0][1] *= i1; accP[1][0][1] *= i1;
        accP[0][1][0] *= i2; accP[1][1][0] *= i2;
        accP[0][1][1] *= i3; accP[1][1][1] *= i3;
    }
    unsigned int pk;
    pk = (unsigned int)f2bf(accP[0][0][0]) | ((unsigned int)f2bf(accP[1][0][0]) << 16);
    *(unsigned int*)(A1 + (size_t)n * 512 + 0 * 128 + lane * 2) = pk;
    pk = (unsigned int)f2bf(accP[0][0][1]) | ((unsigned int)f2bf(accP[1][0][1]) << 16);
    *(unsigned int*)(A1 + (size_t)n * 512 + 1 * 128 + lane * 2) = pk;
    pk = (unsigned int)f2bf(accP[0][1][0]) | ((unsigned int)f2bf(accP[1][1][0]) << 16);
    *(unsigned int*)(A1 + (size_t)n * 512 + 2 * 128 + lane * 2) = pk;
    pk = (unsigned int)f2bf(accP[0][1][1]) | ((unsigned int)f2bf(accP[1][1][1]) << 16);
    *(unsigned int*)(A1 + (size_t)n * 512 + 3 * 128 + lane * 2) = pk;
}

// ------------- l2fused: gemm1h + gemm2 + dots2, minimal LDS ----------------
// Per 64-row block, per head h: MFMA1 P = relu(A1_h @ W1th[h] + b1_h) with
// A/B fragments read directly from global; P -> LDS (stride-72 view);
// MFMA2 h2 += P @ W2t slice (B frags global). Epilogue: h2b write, h2 ->
// LDS (stride-136 view), dots el2/er2 via MFMA vs Qt2 (B frags global).

__global__ __launch_bounds__(256) void l2fused_kernel(
        const unsigned short* __restrict__ A1,    // [N][4][128] bf16
        const unsigned short* __restrict__ W1th,  // [4][64][128] bf16
        const float* __restrict__ b1,             // [256] f32
        const unsigned short* __restrict__ W2t,   // [128][256] bf16
        const unsigned short* __restrict__ Qt2,   // [16][128] bf16
        unsigned short* __restrict__ h2b,         // [N][128] bf16
        float* __restrict__ el2, float* __restrict__ er2,
        int N) {
    constexpr int PP = 72;    // P-tile stride (144B, 16B-aligned rows)
    constexpr int KP = 136;   // h2 staging stride
    __shared__ unsigned short Sh[64 * KP];   // 17.4KB, dual-view
    const int tid = threadIdx.x;
    const int wid = tid >> 6, lane = tid & 63;
    const int lr = lane & 15, lk = (lane >> 4) * 8;
    const int r0 = blockIdx.x * 64;
    const int arow = r0 + wid * 16 + lr;     // this lane's A-frag row
    const bool arok = arow < N;
    const int prow = wid * 16 + (lane >> 4) * 4;

    float4v acc2[8];
    #pragma unroll
    for (int cf = 0; cf < 8; ++cf) acc2[cf] = (float4v){0.f, 0.f, 0.f, 0.f};

    for (int h = 0; h < 4; ++h) {
        // ---- MFMA1: P = A1_h @ W1th[h]^T (frags from global) ----
        float4v p[4];
        #pragma unroll
        for (int cf = 0; cf < 4; ++cf) p[cf] = (float4v){0.f, 0.f, 0.f, 0.f};
        const unsigned short* aptr = A1 + (size_t)arow * 512 + h * 128 + lk;
        const unsigned short* w1p  = W1th + h * 8192 + lr * 128 + lk;
        #pragma unroll
        for (int ks = 0; ks < 128; ks += 32) {
            short8 af = {};
            if (arok) af = *(const short8*)(aptr + ks);
            #pragma unroll
            for (int cf = 0; cf < 4; ++cf) {
                short8 bfr = *(const short8*)(w1p + cf * 2048 + ks);
                p[cf] = __builtin_amdgcn_mfma_f32_16x16x32_bf16(af, bfr, p[cf], 0, 0, 0);
            }
        }
        __syncthreads();  // prior head's MFMA2 reads of Sh complete
        #pragma unroll
        for (int cf = 0; cf < 4; ++cf) {
            float bias = b1[h * 64 + cf * 16 + lr];
            #pragma unroll
            for (int j = 0; j < 4; ++j)
                Sh[(prow + j) * PP + cf * 16 + lr] = f2bf(fmaxf(p[cf][j] + bias, 0.f));
        }
        __syncthreads();
        // ---- MFMA2: h2 += P @ W2t[:, h*64:+64] (B frags from global) ----
        const unsigned short* w2p = W2t + (size_t)lr * 256 + h * 64 + lk;
        #pragma unroll
        for (int ks2 = 0; ks2 < 64; ks2 += 32) {
            short8 af2 = *(const short8*)(Sh + (wid * 16 + lr) * PP + ks2 + lk);
            #pragma unroll
            for (int cf = 0; cf < 8; ++cf) {
                short8 bf2 = *(const short8*)(w2p + cf * 4096 + ks2);
                acc2[cf] = __builtin_amdgcn_mfma_f32_16x16x32_bf16(af2, bf2, acc2[cf], 0, 0, 0);
            }
        }
    }

    __syncthreads();  // all MFMA2 reads done before restaging Sh (KP view)
    // ---- epilogue: write h2b + stage h2 for dots ----
    #pragma unroll
    for (int cf = 0; cf < 8; ++cf) {
        int col = cf * 16 + lr;
        #pragma unroll
        for (int j = 0; j < 4; ++j) {
            unsigned short hv = f2bf(acc2[cf][j]);
            int row = prow + j;
            if (r0 + row < N) h2b[(size_t)(r0 + row) * 128 + col] = hv;
            Sh[row * KP + col] = hv;
        }
    }
    __syncthreads();
    // ---- dots: el2/er2 = h2 @ Qt2 (B frags from global) ----
    float4v dd = (float4v){0.f, 0.f, 0.f, 0.f};
    const unsigned short* qp = Qt2 + lr * 128 + lk;
    #pragma unroll
    for (int ks = 0; ks < 128; ks += 32) {
        short8 af = *(const short8*)(Sh + (wid * 16 + lr) * KP + ks + lk);
        short8 bq = *(const short8*)(qp + ks);
        dd = __builtin_amdgcn_mfma_f32_16x16x32_bf16(af, bq, dd, 0, 0, 0);
    }
    #pragma unroll
    for (int j = 0; j < 4; ++j) {
        int row = r0 + prow + j;
        if (row < N) {
            if (lr == 0) el2[row] = dd[j];
            else if (lr == 1) er2[row] = dd[j];
        }
    }
}

// ---------------------------- agg2 (H=1, D=128, LDS-table) -----------------

__global__ __launch_bounds__(256) void agg2_kernel(const unsigned short* __restrict__ hb,
                           const float* __restrict__ el, const float* __restrict__ er,
                           const int* __restrict__ srcs, const int* __restrict__ row_start,
                           const float* __restrict__ bias, float* __restrict__ out, int N) {
    __shared__ uint2 t_tbl[4][64];
    const int wslot = threadIdx.x >> 6;
    const int lane = threadIdx.x & 63;
    const int n = (blockIdx.x * 256 + threadIdx.x) >> 6;
    if (n >= N) return;
    const int rs = row_start[n];
    const int re = row_start[n + 1];

    float acc0 = 0.f, acc1 = 0.f, d = 0.f;

    if (re > rs) {
        const float ern = er[n];
        for (int base = rs; base < re; base += 64) {
            const int cnt = (re - base) < 64 ? (re - base) : 64;
            asm volatile("s_waitcnt lgkmcnt(0)" ::: "memory");
            if (lane < cnt) {
                int sv = srcs[base + lane];
                float a = __expf(lrelu(el[sv] + ern));
                t_tbl[wslot][lane] = make_uint2((unsigned int)sv, __float_as_uint(a));
            }
            asm volatile("s_waitcnt lgkmcnt(0)" ::: "memory");
            int i = 0;
            for (; i + 4 <= cnt; i += 4) {
                uint2 t0 = t_tbl[wslot][i],     t1 = t_tbl[wslot][i + 1];
                uint2 t2 = t_tbl[wslot][i + 2], t3 = t_tbl[wslot][i + 3];
                float w0 = __uint_as_float(t0.y), w1 = __uint_as_float(t1.y);
                float w2 = __uint_as_float(t2.y), w3 = __uint_as_float(t3.y);
                unsigned int v0 = *(const unsigned int*)(hb + (size_t)t0.x * 128 + lane * 2);
                unsigned int v1 = *(const unsigned int*)(hb + (size_t)t1.x * 128 + lane * 2);
                unsigned int v2 = *(const unsigned int*)(hb + (size_t)t2.x * 128 + lane * 2);
                unsigned int v3 = *(const unsigned int*)(hb + (size_t)t3.x * 128 + lane * 2);
                d += w0 + w1 + w2 + w3;
                acc0 += w0 * bf2f(v0 & 0xffffu) + w1 * bf2f(v1 & 0xffffu) +
                        w2 * bf2f(v2 & 0xffffu) + w3 * bf2f(v3 & 0xffffu);
                acc1 += w0 * bf2f(v0 >> 16) + w1 * bf2f(v1 >> 16) +
                        w2 * bf2f(v2 >> 16) + w3 * bf2f(v3 >> 16);
            }
            for (; i < cnt; ++i) {
                uint2 t = t_tbl[wslot][i];
                float w = __uint_as_float(t.y);
                unsigned int v = *(const unsigned int*)(hb + (size_t)t.x * 128 + lane * 2);
                d += w;
                acc0 += w * bf2f(v & 0xffffu);
                acc1 += w * bf2f(v >> 16);
            }
        }
        float invd = 1.f / d;
        acc0 *= invd; acc1 *= invd;
    }
    float o0 = acc0 + bias[lane * 2];
    float o1 = acc1 + bias[lane * 2 + 1];
    *(float2*)(out + (size_t)n * 128 + lane * 2) = make_float2(o0, o1);
}

// ---------------------------------------------------------------------------

extern "C" void kernel_launch(void* const* d_in, const int* in_sizes, int n_in,
                              void* d_out, int out_size, void* d_ws, size_t ws_size,
                              hipStream_t stream) {
    const float* x   = (const float*)d_in[0];
    const int*   src = (const int*)d_in[1];
    const int*   dst = (const int*)d_in[2];
    const float* W1  = (const float*)d_in[3];
    const float* al1 = (const float*)d_in[4];
    const float* ar1 = (const float*)d_in[5];
    const float* b1  = (const float*)d_in[6];
    const float* W2  = (const float*)d_in[7];
    const float* al2 = (const float*)d_in[8];
    const float* ar2 = (const float*)d_in[9];
    const float* b2  = (const float*)d_in[10];
    float* out = (float*)d_out;

    const int N = in_sizes[0] / 128;  // 50000
    const int E = in_sizes[1];        // 800000
    const int npb = (N + NB - 1) / NB;               // nodes per bucket (196)
    const unsigned int M =
        (unsigned int)(((1ULL << 32) + npb - 1) / (unsigned long long)npb);  // magic div
    const int nblk_e = (E + CH - 1) / CH;            // 98

    char* ws = (char*)d_ws;
    size_t oXB   = 0;                              // xb bf16 [N*128]
    size_t oA1   = oXB + (size_t)N * 128 * 2;      // A1 bf16 [N*4*128]
    size_t oH2   = oA1 + (size_t)N * 512 * 2;      // h2b bf16 [N*128]
    size_t oW1th = oH2 + (size_t)N * 128 * 2;      // [4*64*128] bf16
    size_t oQt1  = oW1th + 32768 * 2;              // [16*128] bf16
    size_t oQt2  = oQt1 + 2048 * 2;                // [16*128] bf16
    size_t oW2t  = oQt2 + 2048 * 2;                // [128*256] bf16
    size_t oEl1  = oW2t + 32768 * 2;               // [N*4] f32
    size_t oEr1  = oEl1 + (size_t)N * 4 * 4;
    size_t oEl2  = oEr1 + (size_t)N * 4 * 4;       // [N] f32
    size_t oEr2  = oEl2 + (size_t)N * 4;
    size_t oRow  = oEr2 + (size_t)N * 4;           // [N+1]
    size_t oBcnt = oRow + (((size_t)(N + 1) * 4 + 15) & ~(size_t)15);  // [nblk_e*NB]
    size_t oCur0 = oBcnt + (size_t)nblk_e * NB * 4;                    // [nblk_e*NB]
    size_t oBkS  = oCur0 + (size_t)nblk_e * NB * 4;                    // [NB+1]
    size_t oPair = (oBkS + (NB + 1) * 4 + 15) & ~(size_t)15;           // [E] uint2
    size_t oSrcs = oPair + (size_t)E * 8;                              // [E]

    unsigned short* xb   = (unsigned short*)(ws + oXB);
    unsigned short* A1   = (unsigned short*)(ws + oA1);
    unsigned short* h2b  = (unsigned short*)(ws + oH2);
    unsigned short* w1th = (unsigned short*)(ws + oW1th);
    unsigned short* qt1  = (unsigned short*)(ws + oQt1);
    unsigned short* qt2  = (unsigned short*)(ws + oQt2);
    unsigned short* w2t  = (unsigned short*)(ws + oW2t);
    float* el1 = (float*)(ws + oEl1);
    float* er1 = (float*)(ws + oEr1);
    float* el2 = (float*)(ws + oEl2);
    float* er2 = (float*)(ws + oEr2);
    int*   row_start   = (int*)(ws + oRow);
    int*   bcnt        = (int*)(ws + oBcnt);
    int*   cur0        = (int*)(ws + oCur0);
    int*   bucketStart = (int*)(ws + oBkS);
    uint2* pairs       = (uint2*)(ws + oPair);
    int*   srcs        = (int*)(ws + oSrcs);

    const int nrowb = (N + 63) / 64;     // 782
    const int nwaveb = (N + 3) / 4;

    // ---- launch 1: bucket histogram + weight prep ----
    histbin_kernel<<<nblk_e + 272, 256, 0, stream>>>(
        dst, bcnt, E, M, nblk_e, W1, al1, ar1, W2, al2, ar2, w1th, qt1, qt2, w2t);

    // ---- launch 2: bin scan -> absolute cursors ----
    binscan_kernel<<<1, 256, 0, stream>>>(bcnt, cur0, bucketStart, nblk_e, E);

    // ---- launch 3: binscatter || xdots ----
    scatxdots_kernel<<<nblk_e + nrowb, 256, 0, stream>>>(
        src, dst, cur0, pairs, E, M, nblk_e,
        x, qt1, xb, el1, er1, N);

    // ---- launch 4: per-bucket CSR ----
    bucketcsr_kernel<<<NB, 256, 0, stream>>>(pairs, bucketStart, row_start, srcs, N, npb, E);

    // ---- launch 5: layer-1 aggregation (x-space) ----
    agg1x_kernel<<<nwaveb, 256, 0, stream>>>(xb, el1, er1, srcs, row_start, A1, N);

    // ---- launch 6: fused gemm1h + gemm2 + dots2 (minimal LDS) ----
    l2fused_kernel<<<nrowb, 256, 0, stream>>>(A1, w1th, b1, w2t, qt2, h2b, el2, er2, N);

    // ---- launch 7: layer-2 aggregation ----
    agg2_kernel<<<nwaveb, 256, 0, stream>>>(h2b, el2, er2, srcs, row_start, b2, out, N);
}

// Round 16
// 191.342 us; speedup vs baseline: 1.1465x; 1.1465x over previous
//
#include <hip/hip_runtime.h>
#include <hip/hip_bf16.h>
#include <math.h>

// ---------------------------------------------------------------------------
// GAT 2-layer forward, MI355X.
// R15->R16: l2fused middle design. R14 (all-LDS, 67KB): 2 blocks/CU, 55us.
// R15 (no-LDS weights): weight frags re-pay L2 latency every MFMA group
// (A1 stream thrashes L1) -> 75us @ 3% MfmaUtil. Now: weights in LDS
// (cross-wave reuse, pipelines with MFMA), A1 frags + Qt2 from global
// (per-lane unique / tiny). LDS 44KB -> 3 blocks/CU. Epilogue h2 staging
// reuses Bs1's region. Everything else unchanged from R15/R13.
// ---------------------------------------------------------------------------

#define NEG_SLOPE 0.2f
#define NB 256        // coarse buckets
#define CH 8192       // edges per binning block

typedef short short8 __attribute__((ext_vector_type(8)));
typedef float float4v __attribute__((ext_vector_type(4)));
typedef float float2v __attribute__((ext_vector_type(2)));

static __device__ __forceinline__ float lrelu(float v) {
    return v > 0.f ? v : NEG_SLOPE * v;
}

static __device__ __forceinline__ unsigned short f2bf(float f) {
    unsigned int u = __float_as_uint(f);
    u = (u + 0x7fffu + ((u >> 16) & 1u)) >> 16;
    return (unsigned short)u;
}
static __device__ __forceinline__ float bf2f(unsigned int lo16) {
    return __uint_as_float(lo16 << 16);
}

static __device__ __forceinline__ int bucket_of(int d, unsigned int M) {
    return (int)(((unsigned long long)(unsigned int)d * M) >> 32);
}

// packed step for agg1x
static __device__ __forceinline__ void pk_step(float2v& a00, float2v& a01,
                                               float2v& a10, float2v& a11,
                                               float2v& d0, float2v& d1,
                                               float4 w, unsigned int v) {
    float2v w01; w01[0] = w.x; w01[1] = w.y;
    float2v w23; w23[0] = w.z; w23[1] = w.w;
    float x0 = __uint_as_float(v << 16);
    float x1 = __uint_as_float(v & 0xffff0000u);
    float2v xx0 = {x0, x0};
    float2v xx1 = {x1, x1};
    asm("v_pk_fma_f32 %0, %1, %2, %0" : "+v"(a00) : "v"(w01), "v"(xx0));
    asm("v_pk_fma_f32 %0, %1, %2, %0" : "+v"(a01) : "v"(w23), "v"(xx0));
    asm("v_pk_fma_f32 %0, %1, %2, %0" : "+v"(a10) : "v"(w01), "v"(xx1));
    asm("v_pk_fma_f32 %0, %1, %2, %0" : "+v"(a11) : "v"(w23), "v"(xx1));
    asm("v_pk_add_f32 %0, %1, %0" : "+v"(d0) : "v"(w01));
    asm("v_pk_add_f32 %0, %1, %0" : "+v"(d1) : "v"(w23));
}

// ---------------------------- P1: bucket histogram + wprep -----------------

__global__ __launch_bounds__(256) void histbin_kernel(
        const int* __restrict__ dst, int* __restrict__ bcnt,
        int E, unsigned int M, int nblk,
        const float* __restrict__ W1, const float* __restrict__ al1,
        const float* __restrict__ ar1, const float* __restrict__ W2,
        const float* __restrict__ al2, const float* __restrict__ ar2,
        unsigned short* __restrict__ W1th, unsigned short* __restrict__ Qt1,
        unsigned short* __restrict__ Qt2, unsigned short* __restrict__ W2t) {
    int b = blockIdx.x;
    int tid = threadIdx.x;
    if (b < nblk) {
        __shared__ int lcnt[NB];
        lcnt[tid] = 0;
        __syncthreads();
        int e0 = b * CH;
        for (int i = tid; i < CH; i += 256) {
            int e = e0 + i;
            if (e < E) atomicAdd(&lcnt[bucket_of(dst[e], M)], 1);
        }
        __syncthreads();
        bcnt[b * NB + tid] = lcnt[tid];
        return;
    }
    int idx = (b - nblk) * 256 + tid;
    if (idx < 32768) {                       // W1th [4][64][128]
        int h = idx >> 13;
        int r = idx & 8191;
        int d = r >> 7, k = r & 127;
        W1th[idx] = f2bf(W1[k * 256 + h * 64 + d]);
    } else if (idx < 34816) {                // Qt1 [16][128]
        int j = idx - 32768;
        int c = j >> 7, k = j & 127;
        float s = 0.f;
        if (c < 8) {
            int h = c & 3;
            const float* av = ((c < 4) ? al1 : ar1) + h * 64;
            const float* wrow = W1 + k * 256 + h * 64;
            #pragma unroll 8
            for (int d = 0; d < 64; ++d) s += wrow[d] * av[d];
        }
        Qt1[j] = f2bf(s);
    } else if (idx < 36864) {                // Qt2 [16][128]
        int j = idx - 34816;
        int c = j >> 7, k = j & 127;
        float s = (c == 0) ? al2[k] : (c == 1) ? ar2[k] : 0.f;
        Qt2[j] = f2bf(s);
    } else if (idx < 69632) {                // W2t [128][256]
        int j = idx - 36864;
        int m = j >> 8, k = j & 255;
        W2t[(size_t)m * 256 + k] = f2bf(W2[(size_t)k * 128 + m]);
    }
}

// ---------------------------- P2: bin scan (1 block) -----------------------

__global__ __launch_bounds__(256) void binscan_kernel(
        const int* __restrict__ bcnt, int* __restrict__ cur0,
        int* __restrict__ bucketStart, int nblk, int E) {
    __shared__ int s[NB];
    int t = threadIdx.x;
    int tot = 0;
    for (int blk = 0; blk < nblk; ++blk) tot += bcnt[blk * NB + t];
    s[t] = tot;
    __syncthreads();
    for (int off = 1; off < NB; off <<= 1) {
        int add = (t >= off) ? s[t - off] : 0;
        __syncthreads();
        s[t] += add;
        __syncthreads();
    }
    const int bs = s[t] - tot;  // exclusive
    bucketStart[t] = bs;
    if (t == NB - 1) bucketStart[NB] = E;
    int run = bs;
    for (int blk = 0; blk < nblk; ++blk) {
        int c = bcnt[blk * NB + t];
        cur0[blk * NB + t] = run;
        run += c;
    }
}

// ------------- P3: fused {binscatter (abs cursors)} | xdots ----------------

__global__ __launch_bounds__(256) void scatxdots_kernel(
        const int* __restrict__ src, const int* __restrict__ dst,
        const int* __restrict__ cur0,
        uint2* __restrict__ pairs, int E, unsigned int M, int nblk,
        const float* __restrict__ x, const unsigned short* __restrict__ Qt,
        unsigned short* __restrict__ xb,
        float* __restrict__ el, float* __restrict__ er, int N) {
    constexpr int KP = 136;
    __shared__ alignas(16) unsigned char smem[(64 + 16) * KP * 2];
    const int tid = threadIdx.x;
    if (blockIdx.x < (unsigned)nblk) {
        int* cur = (int*)smem;           // [NB]
        const int b = blockIdx.x;
        cur[tid] = cur0[b * NB + tid];
        __syncthreads();
        int e0 = b * CH;
        for (int i = tid; i < CH; i += 256) {
            int e = e0 + i;
            if (e < E) {
                int d = dst[e];
                int bk = bucket_of(d, M);
                int pos = atomicAdd(&cur[bk], 1);
                pairs[pos] = make_uint2((unsigned int)src[e], (unsigned int)d);
            }
        }
        return;
    }
    // ---- xdots role ----
    unsigned short* As = (unsigned short*)smem;        // [64*KP]
    unsigned short* Bs = As + 64 * KP;                 // [16*KP]
    const int wid = tid >> 6, lane = tid & 63;
    const int r0 = (blockIdx.x - nblk) * 64;
    for (int ch = tid; ch < 64 * 16; ch += 256) {
        int row = ch >> 4, kc = ch & 15;
        int gr = r0 + row;
        short8 v = {};
        if (gr < N) {
            float4 a = *(const float4*)(x + (size_t)gr * 128 + kc * 8);
            float4 b = *(const float4*)(x + (size_t)gr * 128 + kc * 8 + 4);
            v[0] = (short)f2bf(a.x); v[1] = (short)f2bf(a.y);
            v[2] = (short)f2bf(a.z); v[3] = (short)f2bf(a.w);
            v[4] = (short)f2bf(b.x); v[5] = (short)f2bf(b.y);
            v[6] = (short)f2bf(b.z); v[7] = (short)f2bf(b.w);
            *(short8*)(xb + (size_t)gr * 128 + kc * 8) = v;
        }
        *(short8*)(As + row * KP + kc * 8) = v;
    }
    {
        int row = tid >> 4, kc = tid & 15;
        *(short8*)(Bs + row * KP + kc * 8) = *(const short8*)(Qt + row * 128 + kc * 8);
    }
    __syncthreads();
    float4v acc = (float4v){0.f, 0.f, 0.f, 0.f};
    const int lr = lane & 15, lk = (lane >> 4) * 8;
    #pragma unroll
    for (int ks = 0; ks < 128; ks += 32) {
        short8 af = *(const short8*)(As + (wid * 16 + lr) * KP + ks + lk);
        short8 bf_ = *(const short8*)(Bs + lr * KP + ks + lk);
        acc = __builtin_amdgcn_mfma_f32_16x16x32_bf16(af, bf_, acc, 0, 0, 0);
    }
    const int rbase = r0 + wid * 16 + (lane >> 4) * 4;
    #pragma unroll
    for (int j = 0; j < 4; ++j) {
        int row = rbase + j;
        if (row < N) {
            if (lr < 4) el[(size_t)row * 4 + lr] = acc[j];
            else if (lr < 8) er[(size_t)row * 4 + (lr - 4)] = acc[j];
        }
    }
}

// ---------------------------- P4: per-bucket CSR ---------------------------

__global__ __launch_bounds__(256) void bucketcsr_kernel(
        const uint2* __restrict__ pairs, const int* __restrict__ bucketStart,
        int* __restrict__ row_start, int* __restrict__ srcs,
        int N, int npb, int E) {
    __shared__ int cnt[NB];
    __shared__ int sc[NB];
    int b = blockIdx.x;
    int tid = threadIdx.x;
    int nb0 = b * npb;
    int es = bucketStart[b], ee = bucketStart[b + 1];
    cnt[tid] = 0;
    __syncthreads();
    for (int i = es + tid; i < ee; i += 256) {
        uint2 p = pairs[i];
        atomicAdd(&cnt[(int)p.y - nb0], 1);
    }
    __syncthreads();
    int myc = cnt[tid];
    sc[tid] = myc;
    __syncthreads();
    for (int off = 1; off < NB; off <<= 1) {
        int add = (tid >= off) ? sc[tid - off] : 0;
        __syncthreads();
        sc[tid] += add;
        __syncthreads();
    }
    int excl = sc[tid] - myc;
    int n = nb0 + tid;
    if (n < N && tid < npb) row_start[n] = es + excl;
    if (b == gridDim.x - 1 && tid == 0) row_start[N] = E;
    cnt[tid] = es + excl;   // reuse as cursor
    __syncthreads();
    for (int i = es + tid; i < ee; i += 256) {
        uint2 p = pairs[i];
        int pos = atomicAdd(&cnt[(int)p.y - nb0], 1);
        srcs[pos] = (int)p.x;
    }
}

// ---------------------------- agg1 in x-space (LDS-table + pk math) --------

__global__ __launch_bounds__(256) void agg1x_kernel(const unsigned short* __restrict__ xb,
                            const float* __restrict__ el, const float* __restrict__ er,
                            const int* __restrict__ srcs, const int* __restrict__ row_start,
                            unsigned short* __restrict__ A1, int N) {
    __shared__ int   s_tbl[4][64];
    __shared__ float a_tbl[4][64][4];
    const int wslot = threadIdx.x >> 6;
    const int lane = threadIdx.x & 63;
    const int n = (blockIdx.x * 256 + threadIdx.x) >> 6;
    if (n >= N) return;
    const int rs = row_start[n];
    const int re = row_start[n + 1];

    float2v accP[2][2];
    accP[0][0] = (float2v){0.f, 0.f}; accP[0][1] = (float2v){0.f, 0.f};
    accP[1][0] = (float2v){0.f, 0.f}; accP[1][1] = (float2v){0.f, 0.f};
    float2v dP[2];
    dP[0] = (float2v){0.f, 0.f}; dP[1] = (float2v){0.f, 0.f};

    if (re > rs) {
        const float4 ern = *(const float4*)(er + (size_t)n * 4);
        for (int base = rs; base < re; base += 64) {
            const int cnt = (re - base) < 64 ? (re - base) : 64;
            asm volatile("s_waitcnt lgkmcnt(0)" ::: "memory");
            if (lane < cnt) {
                int sv = srcs[base + lane];
                float4 ev = *(const float4*)(el + (size_t)sv * 4);
                float4 av;
                av.x = __expf(lrelu(ev.x + ern.x));
                av.y = __expf(lrelu(ev.y + ern.y));
                av.z = __expf(lrelu(ev.z + ern.z));
                av.w = __expf(lrelu(ev.w + ern.w));
                s_tbl[wslot][lane] = sv;
                *(float4*)&a_tbl[wslot][lane][0] = av;
            }
            asm volatile("s_waitcnt lgkmcnt(0)" ::: "memory");
            int i = 0;
            for (; i + 4 <= cnt; i += 4) {
                int s0 = s_tbl[wslot][i],     s1 = s_tbl[wslot][i + 1];
                int s2 = s_tbl[wslot][i + 2], s3 = s_tbl[wslot][i + 3];
                float4 w0 = *(const float4*)&a_tbl[wslot][i][0];
                float4 w1 = *(const float4*)&a_tbl[wslot][i + 1][0];
                float4 w2 = *(const float4*)&a_tbl[wslot][i + 2][0];
                float4 w3 = *(const float4*)&a_tbl[wslot][i + 3][0];
                unsigned int v0 = *(const unsigned int*)(xb + (size_t)s0 * 128 + lane * 2);
                unsigned int v1 = *(const unsigned int*)(xb + (size_t)s1 * 128 + lane * 2);
                unsigned int v2 = *(const unsigned int*)(xb + (size_t)s2 * 128 + lane * 2);
                unsigned int v3 = *(const unsigned int*)(xb + (size_t)s3 * 128 + lane * 2);
                pk_step(accP[0][0], accP[0][1], accP[1][0], accP[1][1], dP[0], dP[1], w0, v0);
                pk_step(accP[0][0], accP[0][1], accP[1][0], accP[1][1], dP[0], dP[1], w1, v1);
                pk_step(accP[0][0], accP[0][1], accP[1][0], accP[1][1], dP[0], dP[1], w2, v2);
                pk_step(accP[0][0], accP[0][1], accP[1][0], accP[1][1], dP[0], dP[1], w3, v3);
            }
            for (; i < cnt; ++i) {
                int s0 = s_tbl[wslot][i];
                float4 w = *(const float4*)&a_tbl[wslot][i][0];
                unsigned int v = *(const unsigned int*)(xb + (size_t)s0 * 128 + lane * 2);
                pk_step(accP[0][0], accP[0][1], accP[1][0], accP[1][1], dP[0], dP[1], w, v);
            }
        }
        float i0 = 1.f / dP[0][0], i1 = 1.f / dP[0][1];
        float i2 = 1.f / dP[1][0], i3 = 1.f / dP[1][1];
        accP[0][0][0] *= i0; accP[1][0][0] *= i0;
        accP[0][0][1] *= i1; accP[1][0][1] *= i1;
        accP[0][1][0] *= i2; accP[1][1][0] *= i2;
        accP[0][1][1] *= i3; accP[1][1][1] *= i3;
    }
    unsigned int pk;
    pk = (unsigned int)f2bf(accP[0][0][0]) | ((unsigned int)f2bf(accP[1][0][0]) << 16);
    *(unsigned int*)(A1 + (size_t)n * 512 + 0 * 128 + lane * 2) = pk;
    pk = (unsigned int)f2bf(accP[0][0][1]) | ((unsigned int)f2bf(accP[1][0][1]) << 16);
    *(unsigned int*)(A1 + (size_t)n * 512 + 1 * 128 + lane * 2) = pk;
    pk = (unsigned int)f2bf(accP[0][1][0]) | ((unsigned int)f2bf(accP[1][1][0]) << 16);
    *(unsigned int*)(A1 + (size_t)n * 512 + 2 * 128 + lane * 2) = pk;
    pk = (unsigned int)f2bf(accP[0][1][1]) | ((unsigned int)f2bf(accP[1][1][1]) << 16);
    *(unsigned int*)(A1 + (size_t)n * 512 + 3 * 128 + lane * 2) = pk;
}

// ------------- l2fused: weights in LDS, A1/Qt2 from global -----------------
// Per 64-row block, per head h: stage W1th[h] (Bs1) + W2t slice (Bs2);
// MFMA1 P = relu(A1_h @ W1th[h] + b1_h), A frags global; P -> Ps;
// MFMA2 h2 += P @ Bs2. Epilogue: h2b write; h2 staged into Bs1 (KP view);
// dots el2/er2 via MFMA vs Qt2 (global frags). LDS 44KB -> 3 blocks/CU.

__global__ __launch_bounds__(256) void l2fused_kernel(
        const unsigned short* __restrict__ A1,    // [N][4][128] bf16
        const unsigned short* __restrict__ W1th,  // [4][64][128] bf16
        const float* __restrict__ b1,             // [256] f32
        const unsigned short* __restrict__ W2t,   // [128][256] bf16
        const unsigned short* __restrict__ Qt2,   // [16][128] bf16
        unsigned short* __restrict__ h2b,         // [N][128] bf16
        float* __restrict__ el2, float* __restrict__ er2,
        int N) {
    constexpr int KP = 136;   // Bs1 / h2-staging stride
    constexpr int PP = 72;    // Bs2 / Ps stride
    __shared__ unsigned short Bs1[64 * KP];   // W1th[h]; reused for h2 staging
    __shared__ unsigned short Bs2[128 * PP];  // W2t k-slice
    __shared__ unsigned short Ps[64 * PP];    // P tile
    const int tid = threadIdx.x;
    const int wid = tid >> 6, lane = tid & 63;
    const int lr = lane & 15, lk = (lane >> 4) * 8;
    const int r0 = blockIdx.x * 64;
    const int arow = r0 + wid * 16 + lr;
    const bool arok = arow < N;
    const int prow = wid * 16 + (lane >> 4) * 4;

    float4v acc2[8];
    #pragma unroll
    for (int cf = 0; cf < 8; ++cf) acc2[cf] = (float4v){0.f, 0.f, 0.f, 0.f};

    for (int h = 0; h < 4; ++h) {
        __syncthreads();  // prior head's MFMA reads of Bs1/Bs2 complete
        for (int ch = tid; ch < 1024; ch += 256) {   // Bs1: W1th[h]
            int row = ch >> 4, kc = ch & 15;
            *(short8*)(Bs1 + row * KP + kc * 8) =
                *(const short8*)(W1th + (size_t)h * 8192 + row * 128 + kc * 8);
        }
        for (int ch = tid; ch < 1024; ch += 256) {   // Bs2: W2t[:, h*64:+64]
            int m = ch >> 3, kc = ch & 7;
            *(short8*)(Bs2 + m * PP + kc * 8) =
                *(const short8*)(W2t + (size_t)m * 256 + h * 64 + kc * 8);
        }
        __syncthreads();

        // MFMA1: A frags from global, B from Bs1
        float4v p[4];
        #pragma unroll
        for (int cf = 0; cf < 4; ++cf) p[cf] = (float4v){0.f, 0.f, 0.f, 0.f};
        const unsigned short* aptr = A1 + (size_t)arow * 512 + h * 128 + lk;
        #pragma unroll
        for (int ks = 0; ks < 128; ks += 32) {
            short8 af = {};
            if (arok) af = *(const short8*)(aptr + ks);
            #pragma unroll
            for (int cf = 0; cf < 4; ++cf) {
                short8 bfr = *(const short8*)(Bs1 + (cf * 16 + lr) * KP + ks + lk);
                p[cf] = __builtin_amdgcn_mfma_f32_16x16x32_bf16(af, bfr, p[cf], 0, 0, 0);
            }
        }
        // bias + relu -> Ps  (prior MFMA2 reads of Ps done before loop-top barrier)
        #pragma unroll
        for (int cf = 0; cf < 4; ++cf) {
            float bias = b1[h * 64 + cf * 16 + lr];
            #pragma unroll
            for (int j = 0; j < 4; ++j)
                Ps[(prow + j) * PP + cf * 16 + lr] = f2bf(fmaxf(p[cf][j] + bias, 0.f));
        }
        __syncthreads();
        // MFMA2: h2 += P @ Bs2
        #pragma unroll
        for (int ks2 = 0; ks2 < 64; ks2 += 32) {
            short8 af2 = *(const short8*)(Ps + (wid * 16 + lr) * PP + ks2 + lk);
            #pragma unroll
            for (int cf = 0; cf < 8; ++cf) {
                short8 bf2 = *(const short8*)(Bs2 + (cf * 16 + lr) * PP + ks2 + lk);
                acc2[cf] = __builtin_amdgcn_mfma_f32_16x16x32_bf16(af2, bf2, acc2[cf], 0, 0, 0);
            }
        }
    }

    __syncthreads();  // all MFMA reads done before restaging Bs1 as h2
    #pragma unroll
    for (int cf = 0; cf < 8; ++cf) {
        int col = cf * 16 + lr;
        #pragma unroll
        for (int j = 0; j < 4; ++j) {
            unsigned short hv = f2bf(acc2[cf][j]);
            int row = prow + j;
            if (r0 + row < N) h2b[(size_t)(r0 + row) * 128 + col] = hv;
            Bs1[row * KP + col] = hv;
        }
    }
    __syncthreads();
    float4v dd = (float4v){0.f, 0.f, 0.f, 0.f};
    const unsigned short* qp = Qt2 + lr * 128 + lk;
    #pragma unroll
    for (int ks = 0; ks < 128; ks += 32) {
        short8 af = *(const short8*)(Bs1 + (wid * 16 + lr) * KP + ks + lk);
        short8 bq = *(const short8*)(qp + ks);
        dd = __builtin_amdgcn_mfma_f32_16x16x32_bf16(af, bq, dd, 0, 0, 0);
    }
    #pragma unroll
    for (int j = 0; j < 4; ++j) {
        int row = r0 + prow + j;
        if (row < N) {
            if (lr == 0) el2[row] = dd[j];
            else if (lr == 1) er2[row] = dd[j];
        }
    }
}

// ---------------------------- agg2 (H=1, D=128, LDS-table) -----------------

__global__ __launch_bounds__(256) void agg2_kernel(const unsigned short* __restrict__ hb,
                           const float* __restrict__ el, const float* __restrict__ er,
                           const int* __restrict__ srcs, const int* __restrict__ row_start,
                           const float* __restrict__ bias, float* __restrict__ out, int N) {
    __shared__ uint2 t_tbl[4][64];
    const int wslot = threadIdx.x >> 6;
    const int lane = threadIdx.x & 63;
    const int n = (blockIdx.x * 256 + threadIdx.x) >> 6;
    if (n >= N) return;
    const int rs = row_start[n];
    const int re = row_start[n + 1];

    float acc0 = 0.f, acc1 = 0.f, d = 0.f;

    if (re > rs) {
        const float ern = er[n];
        for (int base = rs; base < re; base += 64) {
            const int cnt = (re - base) < 64 ? (re - base) : 64;
            asm volatile("s_waitcnt lgkmcnt(0)" ::: "memory");
            if (lane < cnt) {
                int sv = srcs[base + lane];
                float a = __expf(lrelu(el[sv] + ern));
                t_tbl[wslot][lane] = make_uint2((unsigned int)sv, __float_as_uint(a));
            }
            asm volatile("s_waitcnt lgkmcnt(0)" ::: "memory");
            int i = 0;
            for (; i + 4 <= cnt; i += 4) {
                uint2 t0 = t_tbl[wslot][i],     t1 = t_tbl[wslot][i + 1];
                uint2 t2 = t_tbl[wslot][i + 2], t3 = t_tbl[wslot][i + 3];
                float w0 = __uint_as_float(t0.y), w1 = __uint_as_float(t1.y);
                float w2 = __uint_as_float(t2.y), w3 = __uint_as_float(t3.y);
                unsigned int v0 = *(const unsigned int*)(hb + (size_t)t0.x * 128 + lane * 2);
                unsigned int v1 = *(const unsigned int*)(hb + (size_t)t1.x * 128 + lane * 2);
                unsigned int v2 = *(const unsigned int*)(hb + (size_t)t2.x * 128 + lane * 2);
                unsigned int v3 = *(const unsigned int*)(hb + (size_t)t3.x * 128 + lane * 2);
                d += w0 + w1 + w2 + w3;
                acc0 += w0 * bf2f(v0 & 0xffffu) + w1 * bf2f(v1 & 0xffffu) +
                        w2 * bf2f(v2 & 0xffffu) + w3 * bf2f(v3 & 0xffffu);
                acc1 += w0 * bf2f(v0 >> 16) + w1 * bf2f(v1 >> 16) +
                        w2 * bf2f(v2 >> 16) + w3 * bf2f(v3 >> 16);
            }
            for (; i < cnt; ++i) {
                uint2 t = t_tbl[wslot][i];
                float w = __uint_as_float(t.y);
                unsigned int v = *(const unsigned int*)(hb + (size_t)t.x * 128 + lane * 2);
                d += w;
                acc0 += w * bf2f(v & 0xffffu);
                acc1 += w * bf2f(v >> 16);
            }
        }
        float invd = 1.f / d;
        acc0 *= invd; acc1 *= invd;
    }
    float o0 = acc0 + bias[lane * 2];
    float o1 = acc1 + bias[lane * 2 + 1];
    *(float2*)(out + (size_t)n * 128 + lane * 2) = make_float2(o0, o1);
}

// ---------------------------------------------------------------------------

extern "C" void kernel_launch(void* const* d_in, const int* in_sizes, int n_in,
                              void* d_out, int out_size, void* d_ws, size_t ws_size,
                              hipStream_t stream) {
    const float* x   = (const float*)d_in[0];
    const int*   src = (const int*)d_in[1];
    const int*   dst = (const int*)d_in[2];
    const float* W1  = (const float*)d_in[3];
    const float* al1 = (const float*)d_in[4];
    const float* ar1 = (const float*)d_in[5];
    const float* b1  = (const float*)d_in[6];
    const float* W2  = (const float*)d_in[7];
    const float* al2 = (const float*)d_in[8];
    const float* ar2 = (const float*)d_in[9];
    const float* b2  = (const float*)d_in[10];
    float* out = (float*)d_out;

    const int N = in_sizes[0] / 128;  // 50000
    const int E = in_sizes[1];        // 800000
    const int npb = (N + NB - 1) / NB;               // nodes per bucket (196)
    const unsigned int M =
        (unsigned int)(((1ULL << 32) + npb - 1) / (unsigned long long)npb);  // magic div
    const int nblk_e = (E + CH - 1) / CH;            // 98

    char* ws = (char*)d_ws;
    size_t oXB   = 0;                              // xb bf16 [N*128]
    size_t oA1   = oXB + (size_t)N * 128 * 2;      // A1 bf16 [N*4*128]
    size_t oH2   = oA1 + (size_t)N * 512 * 2;      // h2b bf16 [N*128]
    size_t oW1th = oH2 + (size_t)N * 128 * 2;      // [4*64*128] bf16
    size_t oQt1  = oW1th + 32768 * 2;              // [16*128] bf16
    size_t oQt2  = oQt1 + 2048 * 2;                // [16*128] bf16
    size_t oW2t  = oQt2 + 2048 * 2;                // [128*256] bf16
    size_t oEl1  = oW2t + 32768 * 2;               // [N*4] f32
    size_t oEr1  = oEl1 + (size_t)N * 4 * 4;
    size_t oEl2  = oEr1 + (size_t)N * 4 * 4;       // [N] f32
    size_t oEr2  = oEl2 + (size_t)N * 4;
    size_t oRow  = oEr2 + (size_t)N * 4;           // [N+1]
    size_t oBcnt = oRow + (((size_t)(N + 1) * 4 + 15) & ~(size_t)15);  // [nblk_e*NB]
    size_t oCur0 = oBcnt + (size_t)nblk_e * NB * 4;                    // [nblk_e*NB]
    size_t oBkS  = oCur0 + (size_t)nblk_e * NB * 4;                    // [NB+1]
    size_t oPair = (oBkS + (NB + 1) * 4 + 15) & ~(size_t)15;           // [E] uint2
    size_t oSrcs = oPair + (size_t)E * 8;                              // [E]

    unsigned short* xb   = (unsigned short*)(ws + oXB);
    unsigned short* A1   = (unsigned short*)(ws + oA1);
    unsigned short* h2b  = (unsigned short*)(ws + oH2);
    unsigned short* w1th = (unsigned short*)(ws + oW1th);
    unsigned short* qt1  = (unsigned short*)(ws + oQt1);
    unsigned short* qt2  = (unsigned short*)(ws + oQt2);
    unsigned short* w2t  = (unsigned short*)(ws + oW2t);
    float* el1 = (float*)(ws + oEl1);
    float* er1 = (float*)(ws + oEr1);
    float* el2 = (float*)(ws + oEl2);
    float* er2 = (float*)(ws + oEr2);
    int*   row_start   = (int*)(ws + oRow);
    int*   bcnt        = (int*)(ws + oBcnt);
    int*   cur0        = (int*)(ws + oCur0);
    int*   bucketStart = (int*)(ws + oBkS);
    uint2* pairs       = (uint2*)(ws + oPair);
    int*   srcs        = (int*)(ws + oSrcs);

    const int nrowb = (N + 63) / 64;     // 782
    const int nwaveb = (N + 3) / 4;

    // ---- launch 1: bucket histogram + weight prep ----
    histbin_kernel<<<nblk_e + 272, 256, 0, stream>>>(
        dst, bcnt, E, M, nblk_e, W1, al1, ar1, W2, al2, ar2, w1th, qt1, qt2, w2t);

    // ---- launch 2: bin scan -> absolute cursors ----
    binscan_kernel<<<1, 256, 0, stream>>>(bcnt, cur0, bucketStart, nblk_e, E);

    // ---- launch 3: binscatter || xdots ----
    scatxdots_kernel<<<nblk_e + nrowb, 256, 0, stream>>>(
        src, dst, cur0, pairs, E, M, nblk_e,
        x, qt1, xb, el1, er1, N);

    // ---- launch 4: per-bucket CSR ----
    bucketcsr_kernel<<<NB, 256, 0, stream>>>(pairs, bucketStart, row_start, srcs, N, npb, E);

    // ---- launch 5: layer-1 aggregation (x-space) ----
    agg1x_kernel<<<nwaveb, 256, 0, stream>>>(xb, el1, er1, srcs, row_start, A1, N);

    // ---- launch 6: fused gemm1h + gemm2 + dots2 (weights-in-LDS) ----
    l2fused_kernel<<<nrowb, 256, 0, stream>>>(A1, w1th, b1, w2t, qt2, h2b, el2, er2, N);

    // ---- launch 7: layer-2 aggregation ----
    agg2_kernel<<<nwaveb, 256, 0, stream>>>(h2b, el2, er2, srcs, row_start, b2, out, N);
}

// Round 17
// 189.731 us; speedup vs baseline: 1.1562x; 1.0085x over previous
//
#include <hip/hip_runtime.h>
#include <hip/hip_bf16.h>
#include <math.h>

// ---------------------------------------------------------------------------
// GAT 2-layer forward, MI355X.
// R16->R17: l2fused A1 prefetch. Three l2fused designs all stalled ~55us
// (44k cyc/block vs ~700 cyc MFMA): the A1 fragment loads (51MB buffer,
// ~half L2-miss -> ~900cy) sit inside the barrier-locked per-head pipeline,
// stalling all resident waves together. Now all 16 A1 frags (4 heads x 4
// k-steps) + 16 biases prefetch at kernel entry — free, since the kernel is
// LDS-capped at 3 blocks/CU and VGPR 68->~135 still allows 12 waves/CU.
// arow clamped (garbage rows stay row-local, dropped at guarded writes).
// Everything else unchanged from R16.
// ---------------------------------------------------------------------------

#define NEG_SLOPE 0.2f
#define NB 256        // coarse buckets
#define CH 8192       // edges per binning block

typedef short short8 __attribute__((ext_vector_type(8)));
typedef float float4v __attribute__((ext_vector_type(4)));
typedef float float2v __attribute__((ext_vector_type(2)));

static __device__ __forceinline__ float lrelu(float v) {
    return v > 0.f ? v : NEG_SLOPE * v;
}

static __device__ __forceinline__ unsigned short f2bf(float f) {
    unsigned int u = __float_as_uint(f);
    u = (u + 0x7fffu + ((u >> 16) & 1u)) >> 16;
    return (unsigned short)u;
}
static __device__ __forceinline__ float bf2f(unsigned int lo16) {
    return __uint_as_float(lo16 << 16);
}

static __device__ __forceinline__ int bucket_of(int d, unsigned int M) {
    return (int)(((unsigned long long)(unsigned int)d * M) >> 32);
}

// packed step for agg1x
static __device__ __forceinline__ void pk_step(float2v& a00, float2v& a01,
                                               float2v& a10, float2v& a11,
                                               float2v& d0, float2v& d1,
                                               float4 w, unsigned int v) {
    float2v w01; w01[0] = w.x; w01[1] = w.y;
    float2v w23; w23[0] = w.z; w23[1] = w.w;
    float x0 = __uint_as_float(v << 16);
    float x1 = __uint_as_float(v & 0xffff0000u);
    float2v xx0 = {x0, x0};
    float2v xx1 = {x1, x1};
    asm("v_pk_fma_f32 %0, %1, %2, %0" : "+v"(a00) : "v"(w01), "v"(xx0));
    asm("v_pk_fma_f32 %0, %1, %2, %0" : "+v"(a01) : "v"(w23), "v"(xx0));
    asm("v_pk_fma_f32 %0, %1, %2, %0" : "+v"(a10) : "v"(w01), "v"(xx1));
    asm("v_pk_fma_f32 %0, %1, %2, %0" : "+v"(a11) : "v"(w23), "v"(xx1));
    asm("v_pk_add_f32 %0, %1, %0" : "+v"(d0) : "v"(w01));
    asm("v_pk_add_f32 %0, %1, %0" : "+v"(d1) : "v"(w23));
}

// ---------------------------- P1: bucket histogram + wprep -----------------

__global__ __launch_bounds__(256) void histbin_kernel(
        const int* __restrict__ dst, int* __restrict__ bcnt,
        int E, unsigned int M, int nblk,
        const float* __restrict__ W1, const float* __restrict__ al1,
        const float* __restrict__ ar1, const float* __restrict__ W2,
        const float* __restrict__ al2, const float* __restrict__ ar2,
        unsigned short* __restrict__ W1th, unsigned short* __restrict__ Qt1,
        unsigned short* __restrict__ Qt2, unsigned short* __restrict__ W2t) {
    int b = blockIdx.x;
    int tid = threadIdx.x;
    if (b < nblk) {
        __shared__ int lcnt[NB];
        lcnt[tid] = 0;
        __syncthreads();
        int e0 = b * CH;
        for (int i = tid; i < CH; i += 256) {
            int e = e0 + i;
            if (e < E) atomicAdd(&lcnt[bucket_of(dst[e], M)], 1);
        }
        __syncthreads();
        bcnt[b * NB + tid] = lcnt[tid];
        return;
    }
    int idx = (b - nblk) * 256 + tid;
    if (idx < 32768) {                       // W1th [4][64][128]
        int h = idx >> 13;
        int r = idx & 8191;
        int d = r >> 7, k = r & 127;
        W1th[idx] = f2bf(W1[k * 256 + h * 64 + d]);
    } else if (idx < 34816) {                // Qt1 [16][128]
        int j = idx - 32768;
        int c = j >> 7, k = j & 127;
        float s = 0.f;
        if (c < 8) {
            int h = c & 3;
            const float* av = ((c < 4) ? al1 : ar1) + h * 64;
            const float* wrow = W1 + k * 256 + h * 64;
            #pragma unroll 8
            for (int d = 0; d < 64; ++d) s += wrow[d] * av[d];
        }
        Qt1[j] = f2bf(s);
    } else if (idx < 36864) {                // Qt2 [16][128]
        int j = idx - 34816;
        int c = j >> 7, k = j & 127;
        float s = (c == 0) ? al2[k] : (c == 1) ? ar2[k] : 0.f;
        Qt2[j] = f2bf(s);
    } else if (idx < 69632) {                // W2t [128][256]
        int j = idx - 36864;
        int m = j >> 8, k = j & 255;
        W2t[(size_t)m * 256 + k] = f2bf(W2[(size_t)k * 128 + m]);
    }
}

// ---------------------------- P2: bin scan (1 block) -----------------------

__global__ __launch_bounds__(256) void binscan_kernel(
        const int* __restrict__ bcnt, int* __restrict__ cur0,
        int* __restrict__ bucketStart, int nblk, int E) {
    __shared__ int s[NB];
    int t = threadIdx.x;
    int tot = 0;
    for (int blk = 0; blk < nblk; ++blk) tot += bcnt[blk * NB + t];
    s[t] = tot;
    __syncthreads();
    for (int off = 1; off < NB; off <<= 1) {
        int add = (t >= off) ? s[t - off] : 0;
        __syncthreads();
        s[t] += add;
        __syncthreads();
    }
    const int bs = s[t] - tot;  // exclusive
    bucketStart[t] = bs;
    if (t == NB - 1) bucketStart[NB] = E;
    int run = bs;
    for (int blk = 0; blk < nblk; ++blk) {
        int c = bcnt[blk * NB + t];
        cur0[blk * NB + t] = run;
        run += c;
    }
}

// ------------- P3: fused {binscatter (abs cursors)} | xdots ----------------

__global__ __launch_bounds__(256) void scatxdots_kernel(
        const int* __restrict__ src, const int* __restrict__ dst,
        const int* __restrict__ cur0,
        uint2* __restrict__ pairs, int E, unsigned int M, int nblk,
        const float* __restrict__ x, const unsigned short* __restrict__ Qt,
        unsigned short* __restrict__ xb,
        float* __restrict__ el, float* __restrict__ er, int N) {
    constexpr int KP = 136;
    __shared__ alignas(16) unsigned char smem[(64 + 16) * KP * 2];
    const int tid = threadIdx.x;
    if (blockIdx.x < (unsigned)nblk) {
        int* cur = (int*)smem;           // [NB]
        const int b = blockIdx.x;
        cur[tid] = cur0[b * NB + tid];
        __syncthreads();
        int e0 = b * CH;
        for (int i = tid; i < CH; i += 256) {
            int e = e0 + i;
            if (e < E) {
                int d = dst[e];
                int bk = bucket_of(d, M);
                int pos = atomicAdd(&cur[bk], 1);
                pairs[pos] = make_uint2((unsigned int)src[e], (unsigned int)d);
            }
        }
        return;
    }
    // ---- xdots role ----
    unsigned short* As = (unsigned short*)smem;        // [64*KP]
    unsigned short* Bs = As + 64 * KP;                 // [16*KP]
    const int wid = tid >> 6, lane = tid & 63;
    const int r0 = (blockIdx.x - nblk) * 64;
    for (int ch = tid; ch < 64 * 16; ch += 256) {
        int row = ch >> 4, kc = ch & 15;
        int gr = r0 + row;
        short8 v = {};
        if (gr < N) {
            float4 a = *(const float4*)(x + (size_t)gr * 128 + kc * 8);
            float4 b = *(const float4*)(x + (size_t)gr * 128 + kc * 8 + 4);
            v[0] = (short)f2bf(a.x); v[1] = (short)f2bf(a.y);
            v[2] = (short)f2bf(a.z); v[3] = (short)f2bf(a.w);
            v[4] = (short)f2bf(b.x); v[5] = (short)f2bf(b.y);
            v[6] = (short)f2bf(b.z); v[7] = (short)f2bf(b.w);
            *(short8*)(xb + (size_t)gr * 128 + kc * 8) = v;
        }
        *(short8*)(As + row * KP + kc * 8) = v;
    }
    {
        int row = tid >> 4, kc = tid & 15;
        *(short8*)(Bs + row * KP + kc * 8) = *(const short8*)(Qt + row * 128 + kc * 8);
    }
    __syncthreads();
    float4v acc = (float4v){0.f, 0.f, 0.f, 0.f};
    const int lr = lane & 15, lk = (lane >> 4) * 8;
    #pragma unroll
    for (int ks = 0; ks < 128; ks += 32) {
        short8 af = *(const short8*)(As + (wid * 16 + lr) * KP + ks + lk);
        short8 bf_ = *(const short8*)(Bs + lr * KP + ks + lk);
        acc = __builtin_amdgcn_mfma_f32_16x16x32_bf16(af, bf_, acc, 0, 0, 0);
    }
    const int rbase = r0 + wid * 16 + (lane >> 4) * 4;
    #pragma unroll
    for (int j = 0; j < 4; ++j) {
        int row = rbase + j;
        if (row < N) {
            if (lr < 4) el[(size_t)row * 4 + lr] = acc[j];
            else if (lr < 8) er[(size_t)row * 4 + (lr - 4)] = acc[j];
        }
    }
}

// ---------------------------- P4: per-bucket CSR ---------------------------

__global__ __launch_bounds__(256) void bucketcsr_kernel(
        const uint2* __restrict__ pairs, const int* __restrict__ bucketStart,
        int* __restrict__ row_start, int* __restrict__ srcs,
        int N, int npb, int E) {
    __shared__ int cnt[NB];
    __shared__ int sc[NB];
    int b = blockIdx.x;
    int tid = threadIdx.x;
    int nb0 = b * npb;
    int es = bucketStart[b], ee = bucketStart[b + 1];
    cnt[tid] = 0;
    __syncthreads();
    for (int i = es + tid; i < ee; i += 256) {
        uint2 p = pairs[i];
        atomicAdd(&cnt[(int)p.y - nb0], 1);
    }
    __syncthreads();
    int myc = cnt[tid];
    sc[tid] = myc;
    __syncthreads();
    for (int off = 1; off < NB; off <<= 1) {
        int add = (tid >= off) ? sc[tid - off] : 0;
        __syncthreads();
        sc[tid] += add;
        __syncthreads();
    }
    int excl = sc[tid] - myc;
    int n = nb0 + tid;
    if (n < N && tid < npb) row_start[n] = es + excl;
    if (b == gridDim.x - 1 && tid == 0) row_start[N] = E;
    cnt[tid] = es + excl;   // reuse as cursor
    __syncthreads();
    for (int i = es + tid; i < ee; i += 256) {
        uint2 p = pairs[i];
        int pos = atomicAdd(&cnt[(int)p.y - nb0], 1);
        srcs[pos] = (int)p.x;
    }
}

// ---------------------------- agg1 in x-space (LDS-table + pk math) --------

__global__ __launch_bounds__(256) void agg1x_kernel(const unsigned short* __restrict__ xb,
                            const float* __restrict__ el, const float* __restrict__ er,
                            const int* __restrict__ srcs, const int* __restrict__ row_start,
                            unsigned short* __restrict__ A1, int N) {
    __shared__ int   s_tbl[4][64];
    __shared__ float a_tbl[4][64][4];
    const int wslot = threadIdx.x >> 6;
    const int lane = threadIdx.x & 63;
    const int n = (blockIdx.x * 256 + threadIdx.x) >> 6;
    if (n >= N) return;
    const int rs = row_start[n];
    const int re = row_start[n + 1];

    float2v accP[2][2];
    accP[0][0] = (float2v){0.f, 0.f}; accP[0][1] = (float2v){0.f, 0.f};
    accP[1][0] = (float2v){0.f, 0.f}; accP[1][1] = (float2v){0.f, 0.f};
    float2v dP[2];
    dP[0] = (float2v){0.f, 0.f}; dP[1] = (float2v){0.f, 0.f};

    if (re > rs) {
        const float4 ern = *(const float4*)(er + (size_t)n * 4);
        for (int base = rs; base < re; base += 64) {
            const int cnt = (re - base) < 64 ? (re - base) : 64;
            asm volatile("s_waitcnt lgkmcnt(0)" ::: "memory");
            if (lane < cnt) {
                int sv = srcs[base + lane];
                float4 ev = *(const float4*)(el + (size_t)sv * 4);
                float4 av;
                av.x = __expf(lrelu(ev.x + ern.x));
                av.y = __expf(lrelu(ev.y + ern.y));
                av.z = __expf(lrelu(ev.z + ern.z));
                av.w = __expf(lrelu(ev.w + ern.w));
                s_tbl[wslot][lane] = sv;
                *(float4*)&a_tbl[wslot][lane][0] = av;
            }
            asm volatile("s_waitcnt lgkmcnt(0)" ::: "memory");
            int i = 0;
            for (; i + 4 <= cnt; i += 4) {
                int s0 = s_tbl[wslot][i],     s1 = s_tbl[wslot][i + 1];
                int s2 = s_tbl[wslot][i + 2], s3 = s_tbl[wslot][i + 3];
                float4 w0 = *(const float4*)&a_tbl[wslot][i][0];
                float4 w1 = *(const float4*)&a_tbl[wslot][i + 1][0];
                float4 w2 = *(const float4*)&a_tbl[wslot][i + 2][0];
                float4 w3 = *(const float4*)&a_tbl[wslot][i + 3][0];
                unsigned int v0 = *(const unsigned int*)(xb + (size_t)s0 * 128 + lane * 2);
                unsigned int v1 = *(const unsigned int*)(xb + (size_t)s1 * 128 + lane * 2);
                unsigned int v2 = *(const unsigned int*)(xb + (size_t)s2 * 128 + lane * 2);
                unsigned int v3 = *(const unsigned int*)(xb + (size_t)s3 * 128 + lane * 2);
                pk_step(accP[0][0], accP[0][1], accP[1][0], accP[1][1], dP[0], dP[1], w0, v0);
                pk_step(accP[0][0], accP[0][1], accP[1][0], accP[1][1], dP[0], dP[1], w1, v1);
                pk_step(accP[0][0], accP[0][1], accP[1][0], accP[1][1], dP[0], dP[1], w2, v2);
                pk_step(accP[0][0], accP[0][1], accP[1][0], accP[1][1], dP[0], dP[1], w3, v3);
            }
            for (; i < cnt; ++i) {
                int s0 = s_tbl[wslot][i];
                float4 w = *(const float4*)&a_tbl[wslot][i][0];
                unsigned int v = *(const unsigned int*)(xb + (size_t)s0 * 128 + lane * 2);
                pk_step(accP[0][0], accP[0][1], accP[1][0], accP[1][1], dP[0], dP[1], w, v);
            }
        }
        float i0 = 1.f / dP[0][0], i1 = 1.f / dP[0][1];
        float i2 = 1.f / dP[1][0], i3 = 1.f / dP[1][1];
        accP[0][0][0] *= i0; accP[1][0][0] *= i0;
        accP[0][0][1] *= i1; accP[1][0][1] *= i1;
        accP[0][1][0] *= i2; accP[1][1][0] *= i2;
        accP[0][1][1] *= i3; accP[1][1][1] *= i3;
    }
    unsigned int pk;
    pk = (unsigned int)f2bf(accP[0][0][0]) | ((unsigned int)f2bf(accP[1][0][0]) << 16);
    *(unsigned int*)(A1 + (size_t)n * 512 + 0 * 128 + lane * 2) = pk;
    pk = (unsigned int)f2bf(accP[0][0][1]) | ((unsigned int)f2bf(accP[1][0][1]) << 16);
    *(unsigned int*)(A1 + (size_t)n * 512 + 1 * 128 + lane * 2) = pk;
    pk = (unsigned int)f2bf(accP[0][1][0]) | ((unsigned int)f2bf(accP[1][1][0]) << 16);
    *(unsigned int*)(A1 + (size_t)n * 512 + 2 * 128 + lane * 2) = pk;
    pk = (unsigned int)f2bf(accP[0][1][1]) | ((unsigned int)f2bf(accP[1][1][1]) << 16);
    *(unsigned int*)(A1 + (size_t)n * 512 + 3 * 128 + lane * 2) = pk;
}

// ------------- l2fused: weights in LDS, A1 prefetched in registers ---------

__global__ __launch_bounds__(256) void l2fused_kernel(
        const unsigned short* __restrict__ A1,    // [N][4][128] bf16
        const unsigned short* __restrict__ W1th,  // [4][64][128] bf16
        const float* __restrict__ b1,             // [256] f32
        const unsigned short* __restrict__ W2t,   // [128][256] bf16
        const unsigned short* __restrict__ Qt2,   // [16][128] bf16
        unsigned short* __restrict__ h2b,         // [N][128] bf16
        float* __restrict__ el2, float* __restrict__ er2,
        int N) {
    constexpr int KP = 136;   // Bs1 / h2-staging stride
    constexpr int PP = 72;    // Bs2 / Ps stride
    __shared__ unsigned short Bs1[64 * KP];   // W1th[h]; reused for h2 staging
    __shared__ unsigned short Bs2[128 * PP];  // W2t k-slice
    __shared__ unsigned short Ps[64 * PP];    // P tile
    const int tid = threadIdx.x;
    const int wid = tid >> 6, lane = tid & 63;
    const int lr = lane & 15, lk = (lane >> 4) * 8;
    const int r0 = blockIdx.x * 64;
    int arow = r0 + wid * 16 + lr;
    if (arow >= N) arow = N - 1;             // clamp: garbage rows stay row-local
    const int prow = wid * 16 + (lane >> 4) * 4;

    // ---- prefetch ALL A1 fragments (4 heads x 4 ksteps) + biases ----
    short8 apre[4][4];
    const unsigned short* abase = A1 + (size_t)arow * 512 + lk;
    #pragma unroll
    for (int h = 0; h < 4; ++h)
        #pragma unroll
        for (int k = 0; k < 4; ++k)
            apre[h][k] = *(const short8*)(abase + h * 128 + k * 32);
    float bpre[4][4];
    #pragma unroll
    for (int h = 0; h < 4; ++h)
        #pragma unroll
        for (int cf = 0; cf < 4; ++cf)
            bpre[h][cf] = b1[h * 64 + cf * 16 + lr];

    float4v acc2[8];
    #pragma unroll
    for (int cf = 0; cf < 8; ++cf) acc2[cf] = (float4v){0.f, 0.f, 0.f, 0.f};

    #pragma unroll
    for (int h = 0; h < 4; ++h) {
        __syncthreads();  // prior head's MFMA reads of Bs1/Bs2/Ps complete
        for (int ch = tid; ch < 1024; ch += 256) {   // Bs1: W1th[h]
            int row = ch >> 4, kc = ch & 15;
            *(short8*)(Bs1 + row * KP + kc * 8) =
                *(const short8*)(W1th + (size_t)h * 8192 + row * 128 + kc * 8);
        }
        for (int ch = tid; ch < 1024; ch += 256) {   // Bs2: W2t[:, h*64:+64]
            int m = ch >> 3, kc = ch & 7;
            *(short8*)(Bs2 + m * PP + kc * 8) =
                *(const short8*)(W2t + (size_t)m * 256 + h * 64 + kc * 8);
        }
        __syncthreads();

        // MFMA1: A frags from registers, B from Bs1
        float4v p[4];
        #pragma unroll
        for (int cf = 0; cf < 4; ++cf) p[cf] = (float4v){0.f, 0.f, 0.f, 0.f};
        #pragma unroll
        for (int k = 0; k < 4; ++k) {
            #pragma unroll
            for (int cf = 0; cf < 4; ++cf) {
                short8 bfr = *(const short8*)(Bs1 + (cf * 16 + lr) * KP + k * 32 + lk);
                p[cf] = __builtin_amdgcn_mfma_f32_16x16x32_bf16(apre[h][k], bfr, p[cf], 0, 0, 0);
            }
        }
        #pragma unroll
        for (int cf = 0; cf < 4; ++cf) {
            float bias = bpre[h][cf];
            #pragma unroll
            for (int j = 0; j < 4; ++j)
                Ps[(prow + j) * PP + cf * 16 + lr] = f2bf(fmaxf(p[cf][j] + bias, 0.f));
        }
        __syncthreads();
        // MFMA2: h2 += P @ Bs2
        #pragma unroll
        for (int ks2 = 0; ks2 < 64; ks2 += 32) {
            short8 af2 = *(const short8*)(Ps + (wid * 16 + lr) * PP + ks2 + lk);
            #pragma unroll
            for (int cf = 0; cf < 8; ++cf) {
                short8 bf2 = *(const short8*)(Bs2 + (cf * 16 + lr) * PP + ks2 + lk);
                acc2[cf] = __builtin_amdgcn_mfma_f32_16x16x32_bf16(af2, bf2, acc2[cf], 0, 0, 0);
            }
        }
    }

    __syncthreads();  // all MFMA reads done before restaging Bs1 as h2
    #pragma unroll
    for (int cf = 0; cf < 8; ++cf) {
        int col = cf * 16 + lr;
        #pragma unroll
        for (int j = 0; j < 4; ++j) {
            unsigned short hv = f2bf(acc2[cf][j]);
            int row = prow + j;
            if (r0 + row < N) h2b[(size_t)(r0 + row) * 128 + col] = hv;
            Bs1[row * KP + col] = hv;
        }
    }
    __syncthreads();
    float4v dd = (float4v){0.f, 0.f, 0.f, 0.f};
    const unsigned short* qp = Qt2 + lr * 128 + lk;
    #pragma unroll
    for (int ks = 0; ks < 128; ks += 32) {
        short8 af = *(const short8*)(Bs1 + (wid * 16 + lr) * KP + ks + lk);
        short8 bq = *(const short8*)(qp + ks);
        dd = __builtin_amdgcn_mfma_f32_16x16x32_bf16(af, bq, dd, 0, 0, 0);
    }
    #pragma unroll
    for (int j = 0; j < 4; ++j) {
        int row = r0 + prow + j;
        if (row < N) {
            if (lr == 0) el2[row] = dd[j];
            else if (lr == 1) er2[row] = dd[j];
        }
    }
}

// ---------------------------- agg2 (H=1, D=128, LDS-table) -----------------

__global__ __launch_bounds__(256) void agg2_kernel(const unsigned short* __restrict__ hb,
                           const float* __restrict__ el, const float* __restrict__ er,
                           const int* __restrict__ srcs, const int* __restrict__ row_start,
                           const float* __restrict__ bias, float* __restrict__ out, int N) {
    __shared__ uint2 t_tbl[4][64];
    const int wslot = threadIdx.x >> 6;
    const int lane = threadIdx.x & 63;
    const int n = (blockIdx.x * 256 + threadIdx.x) >> 6;
    if (n >= N) return;
    const int rs = row_start[n];
    const int re = row_start[n + 1];

    float acc0 = 0.f, acc1 = 0.f, d = 0.f;

    if (re > rs) {
        const float ern = er[n];
        for (int base = rs; base < re; base += 64) {
            const int cnt = (re - base) < 64 ? (re - base) : 64;
            asm volatile("s_waitcnt lgkmcnt(0)" ::: "memory");
            if (lane < cnt) {
                int sv = srcs[base + lane];
                float a = __expf(lrelu(el[sv] + ern));
                t_tbl[wslot][lane] = make_uint2((unsigned int)sv, __float_as_uint(a));
            }
            asm volatile("s_waitcnt lgkmcnt(0)" ::: "memory");
            int i = 0;
            for (; i + 4 <= cnt; i += 4) {
                uint2 t0 = t_tbl[wslot][i],     t1 = t_tbl[wslot][i + 1];
                uint2 t2 = t_tbl[wslot][i + 2], t3 = t_tbl[wslot][i + 3];
                float w0 = __uint_as_float(t0.y), w1 = __uint_as_float(t1.y);
                float w2 = __uint_as_float(t2.y), w3 = __uint_as_float(t3.y);
                unsigned int v0 = *(const unsigned int*)(hb + (size_t)t0.x * 128 + lane * 2);
                unsigned int v1 = *(const unsigned int*)(hb + (size_t)t1.x * 128 + lane * 2);
                unsigned int v2 = *(const unsigned int*)(hb + (size_t)t2.x * 128 + lane * 2);
                unsigned int v3 = *(const unsigned int*)(hb + (size_t)t3.x * 128 + lane * 2);
                d += w0 + w1 + w2 + w3;
                acc0 += w0 * bf2f(v0 & 0xffffu) + w1 * bf2f(v1 & 0xffffu) +
                        w2 * bf2f(v2 & 0xffffu) + w3 * bf2f(v3 & 0xffffu);
                acc1 += w0 * bf2f(v0 >> 16) + w1 * bf2f(v1 >> 16) +
                        w2 * bf2f(v2 >> 16) + w3 * bf2f(v3 >> 16);
            }
            for (; i < cnt; ++i) {
                uint2 t = t_tbl[wslot][i];
                float w = __uint_as_float(t.y);
                unsigned int v = *(const unsigned int*)(hb + (size_t)t.x * 128 + lane * 2);
                d += w;
                acc0 += w * bf2f(v & 0xffffu);
                acc1 += w * bf2f(v >> 16);
            }
        }
        float invd = 1.f / d;
        acc0 *= invd; acc1 *= invd;
    }
    float o0 = acc0 + bias[lane * 2];
    float o1 = acc1 + bias[lane * 2 + 1];
    *(float2*)(out + (size_t)n * 128 + lane * 2) = make_float2(o0, o1);
}

// ---------------------------------------------------------------------------

extern "C" void kernel_launch(void* const* d_in, const int* in_sizes, int n_in,
                              void* d_out, int out_size, void* d_ws, size_t ws_size,
                              hipStream_t stream) {
    const float* x   = (const float*)d_in[0];
    const int*   src = (const int*)d_in[1];
    const int*   dst = (const int*)d_in[2];
    const float* W1  = (const float*)d_in[3];
    const float* al1 = (const float*)d_in[4];
    const float* ar1 = (const float*)d_in[5];
    const float* b1  = (const float*)d_in[6];
    const float* W2  = (const float*)d_in[7];
    const float* al2 = (const float*)d_in[8];
    const float* ar2 = (const float*)d_in[9];
    const float* b2  = (const float*)d_in[10];
    float* out = (float*)d_out;

    const int N = in_sizes[0] / 128;  // 50000
    const int E = in_sizes[1];        // 800000
    const int npb = (N + NB - 1) / NB;               // nodes per bucket (196)
    const unsigned int M =
        (unsigned int)(((1ULL << 32) + npb - 1) / (unsigned long long)npb);  // magic div
    const int nblk_e = (E + CH - 1) / CH;            // 98

    char* ws = (char*)d_ws;
    size_t oXB   = 0;                              // xb bf16 [N*128]
    size_t oA1   = oXB + (size_t)N * 128 * 2;      // A1 bf16 [N*4*128]
    size_t oH2   = oA1 + (size_t)N * 512 * 2;      // h2b bf16 [N*128]
    size_t oW1th = oH2 + (size_t)N * 128 * 2;      // [4*64*128] bf16
    size_t oQt1  = oW1th + 32768 * 2;              // [16*128] bf16
    size_t oQt2  = oQt1 + 2048 * 2;                // [16*128] bf16
    size_t oW2t  = oQt2 + 2048 * 2;                // [128*256] bf16
    size_t oEl1  = oW2t + 32768 * 2;               // [N*4] f32
    size_t oEr1  = oEl1 + (size_t)N * 4 * 4;
    size_t oEl2  = oEr1 + (size_t)N * 4 * 4;       // [N] f32
    size_t oEr2  = oEl2 + (size_t)N * 4;
    size_t oRow  = oEr2 + (size_t)N * 4;           // [N+1]
    size_t oBcnt = oRow + (((size_t)(N + 1) * 4 + 15) & ~(size_t)15);  // [nblk_e*NB]
    size_t oCur0 = oBcnt + (size_t)nblk_e * NB * 4;                    // [nblk_e*NB]
    size_t oBkS  = oCur0 + (size_t)nblk_e * NB * 4;                    // [NB+1]
    size_t oPair = (oBkS + (NB + 1) * 4 + 15) & ~(size_t)15;           // [E] uint2
    size_t oSrcs = oPair + (size_t)E * 8;                              // [E]

    unsigned short* xb   = (unsigned short*)(ws + oXB);
    unsigned short* A1   = (unsigned short*)(ws + oA1);
    unsigned short* h2b  = (unsigned short*)(ws + oH2);
    unsigned short* w1th = (unsigned short*)(ws + oW1th);
    unsigned short* qt1  = (unsigned short*)(ws + oQt1);
    unsigned short* qt2  = (unsigned short*)(ws + oQt2);
    unsigned short* w2t  = (unsigned short*)(ws + oW2t);
    float* el1 = (float*)(ws + oEl1);
    float* er1 = (float*)(ws + oEr1);
    float* el2 = (float*)(ws + oEl2);
    float* er2 = (float*)(ws + oEr2);
    int*   row_start   = (int*)(ws + oRow);
    int*   bcnt        = (int*)(ws + oBcnt);
    int*   cur0        = (int*)(ws + oCur0);
    int*   bucketStart = (int*)(ws + oBkS);
    uint2* pairs       = (uint2*)(ws + oPair);
    int*   srcs        = (int*)(ws + oSrcs);

    const int nrowb = (N + 63) / 64;     // 782
    const int nwaveb = (N + 3) / 4;

    // ---- launch 1: bucket histogram + weight prep ----
    histbin_kernel<<<nblk_e + 272, 256, 0, stream>>>(
        dst, bcnt, E, M, nblk_e, W1, al1, ar1, W2, al2, ar2, w1th, qt1, qt2, w2t);

    // ---- launch 2: bin scan -> absolute cursors ----
    binscan_kernel<<<1, 256, 0, stream>>>(bcnt, cur0, bucketStart, nblk_e, E);

    // ---- launch 3: binscatter || xdots ----
    scatxdots_kernel<<<nblk_e + nrowb, 256, 0, stream>>>(
        src, dst, cur0, pairs, E, M, nblk_e,
        x, qt1, xb, el1, er1, N);

    // ---- launch 4: per-bucket CSR ----
    bucketcsr_kernel<<<NB, 256, 0, stream>>>(pairs, bucketStart, row_start, srcs, N, npb, E);

    // ---- launch 5: layer-1 aggregation (x-space) ----
    agg1x_kernel<<<nwaveb, 256, 0, stream>>>(xb, el1, er1, srcs, row_start, A1, N);

    // ---- launch 6: fused gemm1h + gemm2 + dots2 (A1 prefetched) ----
    l2fused_kernel<<<nrowb, 256, 0, stream>>>(A1, w1th, b1, w2t, qt2, h2b, el2, er2, N);

    // ---- launch 7: layer-2 aggregation ----
    agg2_kernel<<<nwaveb, 256, 0, stream>>>(h2b, el2, er2, srcs, row_start, b2, out, N);
}

// Round 18
// 180.031 us; speedup vs baseline: 1.2185x; 1.0539x over previous
//
#include <hip/hip_runtime.h>
#include <hip/hip_bf16.h>
#include <math.h>

// ---------------------------------------------------------------------------
// GAT 2-layer forward, MI355X.
// R17->R18: l2fused phase-collapse. Five designs all pinned ~54us; model:
// each stage->barrier->MFMA phase costs ~13-17us grid-wide (cf. xdots ~15us,
// same geometry, 1 barrier), and the per-head pipeline had 4 phases. Now:
// wave w owns head w; MFMA1 builds block-diagonal P[64][256] (col=h*64+d)
// in ONE phase (A1 prefetched to regs, W1th[w] frags global/L1); then
// h2 = P @ W2 is ONE K=256 GEMM (wave w owns 32 cols, W2t frags global).
// 3 barriers (was 9); LDS = one 33.8KB P buffer. Everything else unchanged.
// ---------------------------------------------------------------------------

#define NEG_SLOPE 0.2f
#define NB 256        // coarse buckets
#define CH 8192       // edges per binning block

typedef short short8 __attribute__((ext_vector_type(8)));
typedef float float4v __attribute__((ext_vector_type(4)));
typedef float float2v __attribute__((ext_vector_type(2)));

static __device__ __forceinline__ float lrelu(float v) {
    return v > 0.f ? v : NEG_SLOPE * v;
}

static __device__ __forceinline__ unsigned short f2bf(float f) {
    unsigned int u = __float_as_uint(f);
    u = (u + 0x7fffu + ((u >> 16) & 1u)) >> 16;
    return (unsigned short)u;
}
static __device__ __forceinline__ float bf2f(unsigned int lo16) {
    return __uint_as_float(lo16 << 16);
}

static __device__ __forceinline__ int bucket_of(int d, unsigned int M) {
    return (int)(((unsigned long long)(unsigned int)d * M) >> 32);
}

// packed step for agg1x
static __device__ __forceinline__ void pk_step(float2v& a00, float2v& a01,
                                               float2v& a10, float2v& a11,
                                               float2v& d0, float2v& d1,
                                               float4 w, unsigned int v) {
    float2v w01; w01[0] = w.x; w01[1] = w.y;
    float2v w23; w23[0] = w.z; w23[1] = w.w;
    float x0 = __uint_as_float(v << 16);
    float x1 = __uint_as_float(v & 0xffff0000u);
    float2v xx0 = {x0, x0};
    float2v xx1 = {x1, x1};
    asm("v_pk_fma_f32 %0, %1, %2, %0" : "+v"(a00) : "v"(w01), "v"(xx0));
    asm("v_pk_fma_f32 %0, %1, %2, %0" : "+v"(a01) : "v"(w23), "v"(xx0));
    asm("v_pk_fma_f32 %0, %1, %2, %0" : "+v"(a10) : "v"(w01), "v"(xx1));
    asm("v_pk_fma_f32 %0, %1, %2, %0" : "+v"(a11) : "v"(w23), "v"(xx1));
    asm("v_pk_add_f32 %0, %1, %0" : "+v"(d0) : "v"(w01));
    asm("v_pk_add_f32 %0, %1, %0" : "+v"(d1) : "v"(w23));
}

// ---------------------------- P1: bucket histogram + wprep -----------------

__global__ __launch_bounds__(256) void histbin_kernel(
        const int* __restrict__ dst, int* __restrict__ bcnt,
        int E, unsigned int M, int nblk,
        const float* __restrict__ W1, const float* __restrict__ al1,
        const float* __restrict__ ar1, const float* __restrict__ W2,
        const float* __restrict__ al2, const float* __restrict__ ar2,
        unsigned short* __restrict__ W1th, unsigned short* __restrict__ Qt1,
        unsigned short* __restrict__ Qt2, unsigned short* __restrict__ W2t) {
    int b = blockIdx.x;
    int tid = threadIdx.x;
    if (b < nblk) {
        __shared__ int lcnt[NB];
        lcnt[tid] = 0;
        __syncthreads();
        int e0 = b * CH;
        for (int i = tid; i < CH; i += 256) {
            int e = e0 + i;
            if (e < E) atomicAdd(&lcnt[bucket_of(dst[e], M)], 1);
        }
        __syncthreads();
        bcnt[b * NB + tid] = lcnt[tid];
        return;
    }
    int idx = (b - nblk) * 256 + tid;
    if (idx < 32768) {                       // W1th [4][64][128]
        int h = idx >> 13;
        int r = idx & 8191;
        int d = r >> 7, k = r & 127;
        W1th[idx] = f2bf(W1[k * 256 + h * 64 + d]);
    } else if (idx < 34816) {                // Qt1 [16][128]
        int j = idx - 32768;
        int c = j >> 7, k = j & 127;
        float s = 0.f;
        if (c < 8) {
            int h = c & 3;
            const float* av = ((c < 4) ? al1 : ar1) + h * 64;
            const float* wrow = W1 + k * 256 + h * 64;
            #pragma unroll 8
            for (int d = 0; d < 64; ++d) s += wrow[d] * av[d];
        }
        Qt1[j] = f2bf(s);
    } else if (idx < 36864) {                // Qt2 [16][128]
        int j = idx - 34816;
        int c = j >> 7, k = j & 127;
        float s = (c == 0) ? al2[k] : (c == 1) ? ar2[k] : 0.f;
        Qt2[j] = f2bf(s);
    } else if (idx < 69632) {                // W2t [128][256]
        int j = idx - 36864;
        int m = j >> 8, k = j & 255;
        W2t[(size_t)m * 256 + k] = f2bf(W2[(size_t)k * 128 + m]);
    }
}

// ---------------------------- P2: bin scan (1 block) -----------------------

__global__ __launch_bounds__(256) void binscan_kernel(
        const int* __restrict__ bcnt, int* __restrict__ cur0,
        int* __restrict__ bucketStart, int nblk, int E) {
    __shared__ int s[NB];
    int t = threadIdx.x;
    int tot = 0;
    for (int blk = 0; blk < nblk; ++blk) tot += bcnt[blk * NB + t];
    s[t] = tot;
    __syncthreads();
    for (int off = 1; off < NB; off <<= 1) {
        int add = (t >= off) ? s[t - off] : 0;
        __syncthreads();
        s[t] += add;
        __syncthreads();
    }
    const int bs = s[t] - tot;  // exclusive
    bucketStart[t] = bs;
    if (t == NB - 1) bucketStart[NB] = E;
    int run = bs;
    for (int blk = 0; blk < nblk; ++blk) {
        int c = bcnt[blk * NB + t];
        cur0[blk * NB + t] = run;
        run += c;
    }
}

// ------------- P3: fused {binscatter (abs cursors)} | xdots ----------------

__global__ __launch_bounds__(256) void scatxdots_kernel(
        const int* __restrict__ src, const int* __restrict__ dst,
        const int* __restrict__ cur0,
        uint2* __restrict__ pairs, int E, unsigned int M, int nblk,
        const float* __restrict__ x, const unsigned short* __restrict__ Qt,
        unsigned short* __restrict__ xb,
        float* __restrict__ el, float* __restrict__ er, int N) {
    constexpr int KP = 136;
    __shared__ alignas(16) unsigned char smem[(64 + 16) * KP * 2];
    const int tid = threadIdx.x;
    if (blockIdx.x < (unsigned)nblk) {
        int* cur = (int*)smem;           // [NB]
        const int b = blockIdx.x;
        cur[tid] = cur0[b * NB + tid];
        __syncthreads();
        int e0 = b * CH;
        for (int i = tid; i < CH; i += 256) {
            int e = e0 + i;
            if (e < E) {
                int d = dst[e];
                int bk = bucket_of(d, M);
                int pos = atomicAdd(&cur[bk], 1);
                pairs[pos] = make_uint2((unsigned int)src[e], (unsigned int)d);
            }
        }
        return;
    }
    // ---- xdots role ----
    unsigned short* As = (unsigned short*)smem;        // [64*KP]
    unsigned short* Bs = As + 64 * KP;                 // [16*KP]
    const int wid = tid >> 6, lane = tid & 63;
    const int r0 = (blockIdx.x - nblk) * 64;
    for (int ch = tid; ch < 64 * 16; ch += 256) {
        int row = ch >> 4, kc = ch & 15;
        int gr = r0 + row;
        short8 v = {};
        if (gr < N) {
            float4 a = *(const float4*)(x + (size_t)gr * 128 + kc * 8);
            float4 b = *(const float4*)(x + (size_t)gr * 128 + kc * 8 + 4);
            v[0] = (short)f2bf(a.x); v[1] = (short)f2bf(a.y);
            v[2] = (short)f2bf(a.z); v[3] = (short)f2bf(a.w);
            v[4] = (short)f2bf(b.x); v[5] = (short)f2bf(b.y);
            v[6] = (short)f2bf(b.z); v[7] = (short)f2bf(b.w);
            *(short8*)(xb + (size_t)gr * 128 + kc * 8) = v;
        }
        *(short8*)(As + row * KP + kc * 8) = v;
    }
    {
        int row = tid >> 4, kc = tid & 15;
        *(short8*)(Bs + row * KP + kc * 8) = *(const short8*)(Qt + row * 128 + kc * 8);
    }
    __syncthreads();
    float4v acc = (float4v){0.f, 0.f, 0.f, 0.f};
    const int lr = lane & 15, lk = (lane >> 4) * 8;
    #pragma unroll
    for (int ks = 0; ks < 128; ks += 32) {
        short8 af = *(const short8*)(As + (wid * 16 + lr) * KP + ks + lk);
        short8 bf_ = *(const short8*)(Bs + lr * KP + ks + lk);
        acc = __builtin_amdgcn_mfma_f32_16x16x32_bf16(af, bf_, acc, 0, 0, 0);
    }
    const int rbase = r0 + wid * 16 + (lane >> 4) * 4;
    #pragma unroll
    for (int j = 0; j < 4; ++j) {
        int row = rbase + j;
        if (row < N) {
            if (lr < 4) el[(size_t)row * 4 + lr] = acc[j];
            else if (lr < 8) er[(size_t)row * 4 + (lr - 4)] = acc[j];
        }
    }
}

// ---------------------------- P4: per-bucket CSR ---------------------------

__global__ __launch_bounds__(256) void bucketcsr_kernel(
        const uint2* __restrict__ pairs, const int* __restrict__ bucketStart,
        int* __restrict__ row_start, int* __restrict__ srcs,
        int N, int npb, int E) {
    __shared__ int cnt[NB];
    __shared__ int sc[NB];
    int b = blockIdx.x;
    int tid = threadIdx.x;
    int nb0 = b * npb;
    int es = bucketStart[b], ee = bucketStart[b + 1];
    cnt[tid] = 0;
    __syncthreads();
    for (int i = es + tid; i < ee; i += 256) {
        uint2 p = pairs[i];
        atomicAdd(&cnt[(int)p.y - nb0], 1);
    }
    __syncthreads();
    int myc = cnt[tid];
    sc[tid] = myc;
    __syncthreads();
    for (int off = 1; off < NB; off <<= 1) {
        int add = (tid >= off) ? sc[tid - off] : 0;
        __syncthreads();
        sc[tid] += add;
        __syncthreads();
    }
    int excl = sc[tid] - myc;
    int n = nb0 + tid;
    if (n < N && tid < npb) row_start[n] = es + excl;
    if (b == gridDim.x - 1 && tid == 0) row_start[N] = E;
    cnt[tid] = es + excl;   // reuse as cursor
    __syncthreads();
    for (int i = es + tid; i < ee; i += 256) {
        uint2 p = pairs[i];
        int pos = atomicAdd(&cnt[(int)p.y - nb0], 1);
        srcs[pos] = (int)p.x;
    }
}

// ---------------------------- agg1 in x-space (LDS-table + pk math) --------

__global__ __launch_bounds__(256) void agg1x_kernel(const unsigned short* __restrict__ xb,
                            const float* __restrict__ el, const float* __restrict__ er,
                            const int* __restrict__ srcs, const int* __restrict__ row_start,
                            unsigned short* __restrict__ A1, int N) {
    __shared__ int   s_tbl[4][64];
    __shared__ float a_tbl[4][64][4];
    const int wslot = threadIdx.x >> 6;
    const int lane = threadIdx.x & 63;
    const int n = (blockIdx.x * 256 + threadIdx.x) >> 6;
    if (n >= N) return;
    const int rs = row_start[n];
    const int re = row_start[n + 1];

    float2v accP[2][2];
    accP[0][0] = (float2v){0.f, 0.f}; accP[0][1] = (float2v){0.f, 0.f};
    accP[1][0] = (float2v){0.f, 0.f}; accP[1][1] = (float2v){0.f, 0.f};
    float2v dP[2];
    dP[0] = (float2v){0.f, 0.f}; dP[1] = (float2v){0.f, 0.f};

    if (re > rs) {
        const float4 ern = *(const float4*)(er + (size_t)n * 4);
        for (int base = rs; base < re; base += 64) {
            const int cnt = (re - base) < 64 ? (re - base) : 64;
            asm volatile("s_waitcnt lgkmcnt(0)" ::: "memory");
            if (lane < cnt) {
                int sv = srcs[base + lane];
                float4 ev = *(const float4*)(el + (size_t)sv * 4);
                float4 av;
                av.x = __expf(lrelu(ev.x + ern.x));
                av.y = __expf(lrelu(ev.y + ern.y));
                av.z = __expf(lrelu(ev.z + ern.z));
                av.w = __expf(lrelu(ev.w + ern.w));
                s_tbl[wslot][lane] = sv;
                *(float4*)&a_tbl[wslot][lane][0] = av;
            }
            asm volatile("s_waitcnt lgkmcnt(0)" ::: "memory");
            int i = 0;
            for (; i + 4 <= cnt; i += 4) {
                int s0 = s_tbl[wslot][i],     s1 = s_tbl[wslot][i + 1];
                int s2 = s_tbl[wslot][i + 2], s3 = s_tbl[wslot][i + 3];
                float4 w0 = *(const float4*)&a_tbl[wslot][i][0];
                float4 w1 = *(const float4*)&a_tbl[wslot][i + 1][0];
                float4 w2 = *(const float4*)&a_tbl[wslot][i + 2][0];
                float4 w3 = *(const float4*)&a_tbl[wslot][i + 3][0];
                unsigned int v0 = *(const unsigned int*)(xb + (size_t)s0 * 128 + lane * 2);
                unsigned int v1 = *(const unsigned int*)(xb + (size_t)s1 * 128 + lane * 2);
                unsigned int v2 = *(const unsigned int*)(xb + (size_t)s2 * 128 + lane * 2);
                unsigned int v3 = *(const unsigned int*)(xb + (size_t)s3 * 128 + lane * 2);
                pk_step(accP[0][0], accP[0][1], accP[1][0], accP[1][1], dP[0], dP[1], w0, v0);
                pk_step(accP[0][0], accP[0][1], accP[1][0], accP[1][1], dP[0], dP[1], w1, v1);
                pk_step(accP[0][0], accP[0][1], accP[1][0], accP[1][1], dP[0], dP[1], w2, v2);
                pk_step(accP[0][0], accP[0][1], accP[1][0], accP[1][1], dP[0], dP[1], w3, v3);
            }
            for (; i < cnt; ++i) {
                int s0 = s_tbl[wslot][i];
                float4 w = *(const float4*)&a_tbl[wslot][i][0];
                unsigned int v = *(const unsigned int*)(xb + (size_t)s0 * 128 + lane * 2);
                pk_step(accP[0][0], accP[0][1], accP[1][0], accP[1][1], dP[0], dP[1], w, v);
            }
        }
        float i0 = 1.f / dP[0][0], i1 = 1.f / dP[0][1];
        float i2 = 1.f / dP[1][0], i3 = 1.f / dP[1][1];
        accP[0][0][0] *= i0; accP[1][0][0] *= i0;
        accP[0][0][1] *= i1; accP[1][0][1] *= i1;
        accP[0][1][0] *= i2; accP[1][1][0] *= i2;
        accP[0][1][1] *= i3; accP[1][1][1] *= i3;
    }
    unsigned int pk;
    pk = (unsigned int)f2bf(accP[0][0][0]) | ((unsigned int)f2bf(accP[1][0][0]) << 16);
    *(unsigned int*)(A1 + (size_t)n * 512 + 0 * 128 + lane * 2) = pk;
    pk = (unsigned int)f2bf(accP[0][0][1]) | ((unsigned int)f2bf(accP[1][0][1]) << 16);
    *(unsigned int*)(A1 + (size_t)n * 512 + 1 * 128 + lane * 2) = pk;
    pk = (unsigned int)f2bf(accP[0][1][0]) | ((unsigned int)f2bf(accP[1][1][0]) << 16);
    *(unsigned int*)(A1 + (size_t)n * 512 + 2 * 128 + lane * 2) = pk;
    pk = (unsigned int)f2bf(accP[0][1][1]) | ((unsigned int)f2bf(accP[1][1][1]) << 16);
    *(unsigned int*)(A1 + (size_t)n * 512 + 3 * 128 + lane * 2) = pk;
}

// ------------- l2fused: block-diagonal P, single-phase per GEMM ------------
// Wave w owns head w. Phase 1: P[64][256] (col = h*64+d) computed in one
// shot — A1 frags prefetched to regs, W1th[w] frags from global (16KB/wave,
// L1). Phase 2: h2 = P @ W2 as ONE K=256 GEMM; wave w owns 32 output cols,
// W2t frags from global. Phase 3: epilogue (h2b write, restage, dots).
// 3 barriers total. LDS: one P buffer 64x264 (33.8KB), reused at stride 136.

__global__ __launch_bounds__(256) void l2fused_kernel(
        const unsigned short* __restrict__ A1,    // [N][4][128] bf16
        const unsigned short* __restrict__ W1th,  // [4][64][128] bf16
        const float* __restrict__ b1,             // [256] f32
        const unsigned short* __restrict__ W2t,   // [128][256] bf16
        const unsigned short* __restrict__ Qt2,   // [16][128] bf16
        unsigned short* __restrict__ h2b,         // [N][128] bf16
        float* __restrict__ el2, float* __restrict__ er2,
        int N) {
    constexpr int PW = 264;   // P stride (256 + 8): row step 528B -> bank step 4
    constexpr int KP = 136;   // h2 staging stride
    __shared__ unsigned short Sh[64 * PW];  // 33.8KB; KP-view reuse for h2
    const int tid = threadIdx.x;
    const int wid = tid >> 6, lane = tid & 63;
    const int lr = lane & 15, lk = (lane >> 4) * 8;
    const int r0 = blockIdx.x * 64;
    const int prow4 = (lane >> 4) * 4;

    // ---- prefetch A1 frags: rows rf*16+lr, head=wid, kchunks 0..3 ----
    short8 apre[4][4];
    #pragma unroll
    for (int rf = 0; rf < 4; ++rf) {
        int row = r0 + rf * 16 + lr;
        if (row >= N) row = N - 1;   // clamp: garbage rows stay row-local
        const unsigned short* ap = A1 + (size_t)row * 512 + wid * 128 + lk;
        #pragma unroll
        for (int k = 0; k < 4; ++k)
            apre[rf][k] = *(const short8*)(ap + k * 32);
    }
    float bpre[4];
    #pragma unroll
    for (int cf = 0; cf < 4; ++cf) bpre[cf] = b1[wid * 64 + cf * 16 + lr];

    // ---- phase 1: P_head(wid) = A1_head @ W1th[wid]^T ----
    float4v p[4][4];
    #pragma unroll
    for (int rf = 0; rf < 4; ++rf)
        #pragma unroll
        for (int cf = 0; cf < 4; ++cf)
            p[rf][cf] = (float4v){0.f, 0.f, 0.f, 0.f};
    const unsigned short* w1p = W1th + wid * 8192 + lr * 128 + lk;
    #pragma unroll
    for (int k = 0; k < 4; ++k) {
        short8 bfr[4];
        #pragma unroll
        for (int cf = 0; cf < 4; ++cf)
            bfr[cf] = *(const short8*)(w1p + cf * 2048 + k * 32);
        #pragma unroll
        for (int rf = 0; rf < 4; ++rf)
            #pragma unroll
            for (int cf = 0; cf < 4; ++cf)
                p[rf][cf] = __builtin_amdgcn_mfma_f32_16x16x32_bf16(
                    apre[rf][k], bfr[cf], p[rf][cf], 0, 0, 0);
    }
    // bias + relu -> Sh[row][wid*64 + cf*16+lr]
    #pragma unroll
    for (int rf = 0; rf < 4; ++rf)
        #pragma unroll
        for (int cf = 0; cf < 4; ++cf) {
            float bias = bpre[cf];
            #pragma unroll
            for (int j = 0; j < 4; ++j)
                Sh[(rf * 16 + prow4 + j) * PW + wid * 64 + cf * 16 + lr] =
                    f2bf(fmaxf(p[rf][cf][j] + bias, 0.f));
        }
    __syncthreads();

    // ---- phase 2: h2 = P @ W2 (K=256); wave owns cols [wid*32, wid*32+32) ----
    float4v acc2[4][2];
    #pragma unroll
    for (int rf = 0; rf < 4; ++rf) {
        acc2[rf][0] = (float4v){0.f, 0.f, 0.f, 0.f};
        acc2[rf][1] = (float4v){0.f, 0.f, 0.f, 0.f};
    }
    const unsigned short* w2p = W2t + (size_t)(wid * 32 + lr) * 256 + lk;
    #pragma unroll
    for (int kk = 0; kk < 8; ++kk) {
        short8 bq0 = *(const short8*)(w2p + kk * 32);
        short8 bq1 = *(const short8*)(w2p + 16 * 256 + kk * 32);
        #pragma unroll
        for (int rf = 0; rf < 4; ++rf) {
            short8 af = *(const short8*)(Sh + (rf * 16 + lr) * PW + kk * 32 + lk);
            acc2[rf][0] = __builtin_amdgcn_mfma_f32_16x16x32_bf16(af, bq0, acc2[rf][0], 0, 0, 0);
            acc2[rf][1] = __builtin_amdgcn_mfma_f32_16x16x32_bf16(af, bq1, acc2[rf][1], 0, 0, 0);
        }
    }
    __syncthreads();  // all P reads done before restaging Sh at KP stride

    // ---- phase 3: h2b write + restage + dots ----
    #pragma unroll
    for (int rf = 0; rf < 4; ++rf)
        #pragma unroll
        for (int cf = 0; cf < 2; ++cf) {
            int col = wid * 32 + cf * 16 + lr;
            #pragma unroll
            for (int j = 0; j < 4; ++j) {
                unsigned short hv = f2bf(acc2[rf][cf][j]);
                int row = rf * 16 + prow4 + j;
                if (r0 + row < N) h2b[(size_t)(r0 + row) * 128 + col] = hv;
                Sh[row * KP + col] = hv;
            }
        }
    __syncthreads();
    float4v dd = (float4v){0.f, 0.f, 0.f, 0.f};
    const unsigned short* qp = Qt2 + lr * 128 + lk;
    #pragma unroll
    for (int ks = 0; ks < 128; ks += 32) {
        short8 af = *(const short8*)(Sh + (wid * 16 + lr) * KP + ks + lk);
        short8 bq = *(const short8*)(qp + ks);
        dd = __builtin_amdgcn_mfma_f32_16x16x32_bf16(af, bq, dd, 0, 0, 0);
    }
    #pragma unroll
    for (int j = 0; j < 4; ++j) {
        int row = r0 + wid * 16 + prow4 + j;
        if (row < N) {
            if (lr == 0) el2[row] = dd[j];
            else if (lr == 1) er2[row] = dd[j];
        }
    }
}

// ---------------------------- agg2 (H=1, D=128, LDS-table) -----------------

__global__ __launch_bounds__(256) void agg2_kernel(const unsigned short* __restrict__ hb,
                           const float* __restrict__ el, const float* __restrict__ er,
                           const int* __restrict__ srcs, const int* __restrict__ row_start,
                           const float* __restrict__ bias, float* __restrict__ out, int N) {
    __shared__ uint2 t_tbl[4][64];
    const int wslot = threadIdx.x >> 6;
    const int lane = threadIdx.x & 63;
    const int n = (blockIdx.x * 256 + threadIdx.x) >> 6;
    if (n >= N) return;
    const int rs = row_start[n];
    const int re = row_start[n + 1];

    float acc0 = 0.f, acc1 = 0.f, d = 0.f;

    if (re > rs) {
        const float ern = er[n];
        for (int base = rs; base < re; base += 64) {
            const int cnt = (re - base) < 64 ? (re - base) : 64;
            asm volatile("s_waitcnt lgkmcnt(0)" ::: "memory");
            if (lane < cnt) {
                int sv = srcs[base + lane];
                float a = __expf(lrelu(el[sv] + ern));
                t_tbl[wslot][lane] = make_uint2((unsigned int)sv, __float_as_uint(a));
            }
            asm volatile("s_waitcnt lgkmcnt(0)" ::: "memory");
            int i = 0;
            for (; i + 4 <= cnt; i += 4) {
                uint2 t0 = t_tbl[wslot][i],     t1 = t_tbl[wslot][i + 1];
                uint2 t2 = t_tbl[wslot][i + 2], t3 = t_tbl[wslot][i + 3];
                float w0 = __uint_as_float(t0.y), w1 = __uint_as_float(t1.y);
                float w2 = __uint_as_float(t2.y), w3 = __uint_as_float(t3.y);
                unsigned int v0 = *(const unsigned int*)(hb + (size_t)t0.x * 128 + lane * 2);
                unsigned int v1 = *(const unsigned int*)(hb + (size_t)t1.x * 128 + lane * 2);
                unsigned int v2 = *(const unsigned int*)(hb + (size_t)t2.x * 128 + lane * 2);
                unsigned int v3 = *(const unsigned int*)(hb + (size_t)t3.x * 128 + lane * 2);
                d += w0 + w1 + w2 + w3;
                acc0 += w0 * bf2f(v0 & 0xffffu) + w1 * bf2f(v1 & 0xffffu) +
                        w2 * bf2f(v2 & 0xffffu) + w3 * bf2f(v3 & 0xffffu);
                acc1 += w0 * bf2f(v0 >> 16) + w1 * bf2f(v1 >> 16) +
                        w2 * bf2f(v2 >> 16) + w3 * bf2f(v3 >> 16);
            }
            for (; i < cnt; ++i) {
                uint2 t = t_tbl[wslot][i];
                float w = __uint_as_float(t.y);
                unsigned int v = *(const unsigned int*)(hb + (size_t)t.x * 128 + lane * 2);
                d += w;
                acc0 += w * bf2f(v & 0xffffu);
                acc1 += w * bf2f(v >> 16);
            }
        }
        float invd = 1.f / d;
        acc0 *= invd; acc1 *= invd;
    }
    float o0 = acc0 + bias[lane * 2];
    float o1 = acc1 + bias[lane * 2 + 1];
    *(float2*)(out + (size_t)n * 128 + lane * 2) = make_float2(o0, o1);
}

// ---------------------------------------------------------------------------

extern "C" void kernel_launch(void* const* d_in, const int* in_sizes, int n_in,
                              void* d_out, int out_size, void* d_ws, size_t ws_size,
                              hipStream_t stream) {
    const float* x   = (const float*)d_in[0];
    const int*   src = (const int*)d_in[1];
    const int*   dst = (const int*)d_in[2];
    const float* W1  = (const float*)d_in[3];
    const float* al1 = (const float*)d_in[4];
    const float* ar1 = (const float*)d_in[5];
    const float* b1  = (const float*)d_in[6];
    const float* W2  = (const float*)d_in[7];
    const float* al2 = (const float*)d_in[8];
    const float* ar2 = (const float*)d_in[9];
    const float* b2  = (const float*)d_in[10];
    float* out = (float*)d_out;

    const int N = in_sizes[0] / 128;  // 50000
    const int E = in_sizes[1];        // 800000
    const int npb = (N + NB - 1) / NB;               // nodes per bucket (196)
    const unsigned int M =
        (unsigned int)(((1ULL << 32) + npb - 1) / (unsigned long long)npb);  // magic div
    const int nblk_e = (E + CH - 1) / CH;            // 98

    char* ws = (char*)d_ws;
    size_t oXB   = 0;                              // xb bf16 [N*128]
    size_t oA1   = oXB + (size_t)N * 128 * 2;      // A1 bf16 [N*4*128]
    size_t oH2   = oA1 + (size_t)N * 512 * 2;      // h2b bf16 [N*128]
    size_t oW1th = oH2 + (size_t)N * 128 * 2;      // [4*64*128] bf16
    size_t oQt1  = oW1th + 32768 * 2;              // [16*128] bf16
    size_t oQt2  = oQt1 + 2048 * 2;                // [16*128] bf16
    size_t oW2t  = oQt2 + 2048 * 2;                // [128*256] bf16
    size_t oEl1  = oW2t + 32768 * 2;               // [N*4] f32
    size_t oEr1  = oEl1 + (size_t)N * 4 * 4;
    size_t oEl2  = oEr1 + (size_t)N * 4 * 4;       // [N] f32
    size_t oEr2  = oEl2 + (size_t)N * 4;
    size_t oRow  = oEr2 + (size_t)N * 4;           // [N+1]
    size_t oBcnt = oRow + (((size_t)(N + 1) * 4 + 15) & ~(size_t)15);  // [nblk_e*NB]
    size_t oCur0 = oBcnt + (size_t)nblk_e * NB * 4;                    // [nblk_e*NB]
    size_t oBkS  = oCur0 + (size_t)nblk_e * NB * 4;                    // [NB+1]
    size_t oPair = (oBkS + (NB + 1) * 4 + 15) & ~(size_t)15;           // [E] uint2
    size_t oSrcs = oPair + (size_t)E * 8;                              // [E]

    unsigned short* xb   = (unsigned short*)(ws + oXB);
    unsigned short* A1   = (unsigned short*)(ws + oA1);
    unsigned short* h2b  = (unsigned short*)(ws + oH2);
    unsigned short* w1th = (unsigned short*)(ws + oW1th);
    unsigned short* qt1  = (unsigned short*)(ws + oQt1);
    unsigned short* qt2  = (unsigned short*)(ws + oQt2);
    unsigned short* w2t  = (unsigned short*)(ws + oW2t);
    float* el1 = (float*)(ws + oEl1);
    float* er1 = (float*)(ws + oEr1);
    float* el2 = (float*)(ws + oEl2);
    float* er2 = (float*)(ws + oEr2);
    int*   row_start   = (int*)(ws + oRow);
    int*   bcnt        = (int*)(ws + oBcnt);
    int*   cur0        = (int*)(ws + oCur0);
    int*   bucketStart = (int*)(ws + oBkS);
    uint2* pairs       = (uint2*)(ws + oPair);
    int*   srcs        = (int*)(ws + oSrcs);

    const int nrowb = (N + 63) / 64;     // 782
    const int nwaveb = (N + 3) / 4;

    // ---- launch 1: bucket histogram + weight prep ----
    histbin_kernel<<<nblk_e + 272, 256, 0, stream>>>(
        dst, bcnt, E, M, nblk_e, W1, al1, ar1, W2, al2, ar2, w1th, qt1, qt2, w2t);

    // ---- launch 2: bin scan -> absolute cursors ----
    binscan_kernel<<<1, 256, 0, stream>>>(bcnt, cur0, bucketStart, nblk_e, E);

    // ---- launch 3: binscatter || xdots ----
    scatxdots_kernel<<<nblk_e + nrowb, 256, 0, stream>>>(
        src, dst, cur0, pairs, E, M, nblk_e,
        x, qt1, xb, el1, er1, N);

    // ---- launch 4: per-bucket CSR ----
    bucketcsr_kernel<<<NB, 256, 0, stream>>>(pairs, bucketStart, row_start, srcs, N, npb, E);

    // ---- launch 5: layer-1 aggregation (x-space) ----
    agg1x_kernel<<<nwaveb, 256, 0, stream>>>(xb, el1, er1, srcs, row_start, A1, N);

    // ---- launch 6: fused gemm1h + gemm2 + dots2 (block-diagonal P) ----
    l2fused_kernel<<<nrowb, 256, 0, stream>>>(A1, w1th, b1, w2t, qt2, h2b, el2, er2, N);

    // ---- launch 7: layer-2 aggregation ----
    agg2_kernel<<<nwaveb, 256, 0, stream>>>(h2b, el2, er2, srcs, row_start, b2, out, N);
}